// Round 5
// baseline (239.672 us; speedup 1.0000x reference)
//
#include <hip/hip_runtime.h>
#include <hip/hip_fp16.h>

#define NB 2
#define RAYS 4096
#define SAMP 96
#define CF 32
#define HID 64
#define HW 256

constexpr int M_TOTAL = NB * RAYS * SAMP;   // 786432 samples

typedef _Float16 f16x8 __attribute__((ext_vector_type(8)));
typedef float f32x4 __attribute__((ext_vector_type(4)));
typedef int i32x4 __attribute__((ext_vector_type(4)));

__device__ __forceinline__ float softplus_f(float z) {
    return fmaxf(z, 0.f) + __logf(1.f + __expf(-fabsf(z)));
}
__device__ __forceinline__ float sigmoid_f(float z) {
    return __fdividef(1.f, 1.f + __expf(-z));
}

// planes (N,3,C,H,W) f32  ->  pt (N*3, H, W, C) f16  (channel-interleaved)
__global__ __launch_bounds__(256)
void k_transpose(const float* __restrict__ src, __half2* __restrict__ dst) {
    int i = blockIdx.x * 256 + threadIdx.x;   // over 6*65536*16 half2 outputs
    int c2 = i & 15;
    int xy = (i >> 4) & 0xFFFF;
    int pn = i >> 20;                          // n*3+p  in [0,6)
    const float* s = src + (((size_t)(pn * CF + c2 * 2)) << 16) + xy;
    float a = s[0];
    float b = s[(size_t)1 << 16];
    dst[((size_t)(pn) << 16) * 16 + (size_t)xy * 16 + c2] = __floats2half2_rn(a, b);
}

// ======================= split path: gather + MLP =======================
// 2-wave (128-thread) blocks: per-wave 9216B LDS slice -> 18KiB/block.
// Limits: LDS 8 blk/CU, WG-slots 8, VGPR(<=128) 4 waves/SIMD  => 16 waves/CU (50%).
constexpr int TG = 128;         // threads per gmlp block
constexpr int SLICE_A = 9216;   // per-wave LDS slice bytes
constexpr int SIGO = 5120;      // sigma region within slice (float[64])
// xS / rgb rows: row*80 (+ c*16 / + c*2);  hS rows: row*144

__global__ __launch_bounds__(TG, 4)
void k_gmlp(const __half2* __restrict__ pt, const float* __restrict__ coords,
            const float* __restrict__ w1, const float* __restrict__ b1,
            const float* __restrict__ w2, const float* __restrict__ b2,
            __half* __restrict__ rgbW, float* __restrict__ sigW)
{
    __shared__ __align__(16) char sm[(TG / 64) * SLICE_A];
    const int t = threadIdx.x;
    const int wv = t >> 6;                 // wave id
    const int l = t & 63;
    const int g = l >> 4;
    const int ln = l & 15;
    char* const slice = sm + wv * SLICE_A;

    const int msamp = blockIdx.x * TG + t;
    const int nb = (msamp >= M_TOTAL / NB) ? 1 : 0;

    // ---- weight fragments in registers ----
    f16x8 b1f[4];
    float b1v[4];
    #pragma unroll
    for (int Nt = 0; Nt < 4; ++Nt) {
        const int hn = 16 * Nt + ln;
        const float4* p0 = (const float4*)(w1 + hn * CF + g * 8);
        float4 u = p0[0], v = p0[1];
        b1f[Nt][0] = (_Float16)u.x; b1f[Nt][1] = (_Float16)u.y;
        b1f[Nt][2] = (_Float16)u.z; b1f[Nt][3] = (_Float16)u.w;
        b1f[Nt][4] = (_Float16)v.x; b1f[Nt][5] = (_Float16)v.y;
        b1f[Nt][6] = (_Float16)v.z; b1f[Nt][7] = (_Float16)v.w;
        b1v[Nt] = b1[hn];
    }
    f16x8 b2f[3][2];
    float b2v[3];
    #pragma unroll
    for (int Nt2 = 0; Nt2 < 3; ++Nt2) {
        const int o = 16 * Nt2 + ln;
        if (o < 33) {
            #pragma unroll
            for (int kh = 0; kh < 2; ++kh) {
                const float4* p0 = (const float4*)(w2 + o * HID + kh * 32 + g * 8);
                float4 u = p0[0], v = p0[1];
                b2f[Nt2][kh][0] = (_Float16)u.x; b2f[Nt2][kh][1] = (_Float16)u.y;
                b2f[Nt2][kh][2] = (_Float16)u.z; b2f[Nt2][kh][3] = (_Float16)u.w;
                b2f[Nt2][kh][4] = (_Float16)v.x; b2f[Nt2][kh][5] = (_Float16)v.y;
                b2f[Nt2][kh][6] = (_Float16)v.z; b2f[Nt2][kh][7] = (_Float16)v.w;
            }
            b2v[Nt2] = b2[o];
        } else {
            #pragma unroll
            for (int kh = 0; kh < 2; ++kh)
                #pragma unroll
                for (int i = 0; i < 8; ++i) b2f[Nt2][kh][i] = (_Float16)0.f;
            b2v[Nt2] = 0.f;
        }
    }

    // ---- gather ----
    const float* cp = coords + (size_t)msamp * 3;
    const float c0 = cp[0], c1 = cp[1], c2v = cp[2];

    __half2 acc[16];
    #pragma unroll
    for (int k = 0; k < 16; ++k) acc[k] = __float2half2_rn(0.f);

    #pragma unroll
    for (int p = 0; p < 3; ++p) {
        const float u = (p == 2) ? c2v : c0;
        const float v = (p == 0) ? c1 : ((p == 1) ? c2v : c0);
        const float xf = fmaf(u, 128.f, 127.5f);
        const float yf = fmaf(v, 128.f, 127.5f);
        const float x0f = floorf(xf), y0f = floorf(yf);
        const float wx = xf - x0f, wy = yf - y0f;
        const int x0 = (int)x0f, y0 = (int)y0f;
        const float vx0 = (x0 >= 0 && x0 < HW) ? 1.f : 0.f;
        const float vx1 = (x0 + 1 >= 0 && x0 + 1 < HW) ? 1.f : 0.f;
        const float vy0 = (y0 >= 0 && y0 < HW) ? 1.f : 0.f;
        const float vy1 = (y0 + 1 >= 0 && y0 + 1 < HW) ? 1.f : 0.f;
        const int xc0 = min(max(x0, 0), HW - 1), xc1 = min(max(x0 + 1, 0), HW - 1);
        const int yc0 = min(max(y0, 0), HW - 1), yc1 = min(max(y0 + 1, 0), HW - 1);
        const float w00 = (1.f - wx) * (1.f - wy) * vx0 * vy0;
        const float w10 = wx * (1.f - wy) * vx1 * vy0;
        const float w01 = (1.f - wx) * wy * vx0 * vy1;
        const float w11 = wx * wy * vx1 * vy1;

        const __half2* pb = pt + ((size_t)(nb * 3 + p) << 16) * 16;
        auto tap = [&](int yc, int xc, float w) {
            const float4* tp = (const float4*)(pb + (size_t)(yc * HW + xc) * 16);
            const __half2 wh = __float2half2_rn(w);
            #pragma unroll
            for (int q = 0; q < 4; ++q) {
                union { float4 f; __half2 h[4]; } u4;
                u4.f = tp[q];
                acc[q * 4 + 0] = __hfma2(wh, u4.h[0], acc[q * 4 + 0]);
                acc[q * 4 + 1] = __hfma2(wh, u4.h[1], acc[q * 4 + 1]);
                acc[q * 4 + 2] = __hfma2(wh, u4.h[2], acc[q * 4 + 2]);
                acc[q * 4 + 3] = __hfma2(wh, u4.h[3], acc[q * 4 + 3]);
            }
        };
        tap(yc0, xc0, w00);
        tap(yc0, xc1, w10);
        tap(yc1, xc0, w01);
        tap(yc1, xc1, w11);
    }

    // ---- stage x ----
    const __half2 third = __float2half2_rn(1.f / 3.f);
    #pragma unroll
    for (int c = 0; c < 4; ++c) {
        union { __half2 h[4]; i32x4 v; } u4;
        #pragma unroll
        for (int j = 0; j < 4; ++j) u4.h[j] = __hmul2(acc[4 * c + j], third);
        *(i32x4*)(slice + l * 80 + c * 16) = u4.v;
    }

    // ---- layer 1 ----
    f16x8 a1[4];
    #pragma unroll
    for (int Mt = 0; Mt < 4; ++Mt)
        a1[Mt] = *(const f16x8*)(slice + (16 * Mt + ln) * 80 + g * 16);

    constexpr float is32 = 0.17677669529663687f;
    #pragma unroll
    for (int Nt = 0; Nt < 4; ++Nt) {
        f32x4 d0 = {0.f, 0.f, 0.f, 0.f};
        f32x4 d1 = {0.f, 0.f, 0.f, 0.f};
        f32x4 d2 = {0.f, 0.f, 0.f, 0.f};
        f32x4 d3 = {0.f, 0.f, 0.f, 0.f};
        d0 = __builtin_amdgcn_mfma_f32_16x16x32_f16(a1[0], b1f[Nt], d0, 0, 0, 0);
        d1 = __builtin_amdgcn_mfma_f32_16x16x32_f16(a1[1], b1f[Nt], d1, 0, 0, 0);
        d2 = __builtin_amdgcn_mfma_f32_16x16x32_f16(a1[2], b1f[Nt], d2, 0, 0, 0);
        d3 = __builtin_amdgcn_mfma_f32_16x16x32_f16(a1[3], b1f[Nt], d3, 0, 0, 0);
        const int hcol = 16 * Nt + ln;
        #pragma unroll
        for (int Mt = 0; Mt < 4; ++Mt) {
            f32x4 dd = (Mt == 0) ? d0 : (Mt == 1) ? d1 : (Mt == 2) ? d2 : d3;
            #pragma unroll
            for (int r = 0; r < 4; ++r) {
                const float hv = softplus_f(fmaf(dd[r], is32, b1v[Nt]));
                const int row = 16 * Mt + 4 * g + r;
                *(__half*)(slice + row * 144 + hcol * 2) = __float2half(hv);
            }
        }
    }

    // ---- layer 2 ----
    f16x8 a2[4][2];
    #pragma unroll
    for (int Mt = 0; Mt < 4; ++Mt)
        #pragma unroll
        for (int kh = 0; kh < 2; ++kh)
            a2[Mt][kh] = *(const f16x8*)(slice + (16 * Mt + ln) * 144 + (kh * 4 + g) * 16);

    #pragma unroll
    for (int Nt2 = 0; Nt2 < 3; ++Nt2) {
        f32x4 e0 = {0.f, 0.f, 0.f, 0.f};
        f32x4 e1 = {0.f, 0.f, 0.f, 0.f};
        f32x4 e2 = {0.f, 0.f, 0.f, 0.f};
        f32x4 e3 = {0.f, 0.f, 0.f, 0.f};
        #pragma unroll
        for (int kh = 0; kh < 2; ++kh) {
            e0 = __builtin_amdgcn_mfma_f32_16x16x32_f16(a2[0][kh], b2f[Nt2][kh], e0, 0, 0, 0);
            e1 = __builtin_amdgcn_mfma_f32_16x16x32_f16(a2[1][kh], b2f[Nt2][kh], e1, 0, 0, 0);
            e2 = __builtin_amdgcn_mfma_f32_16x16x32_f16(a2[2][kh], b2f[Nt2][kh], e2, 0, 0, 0);
            e3 = __builtin_amdgcn_mfma_f32_16x16x32_f16(a2[3][kh], b2f[Nt2][kh], e3, 0, 0, 0);
        }
        const int o = 16 * Nt2 + ln;
        if (o == 0) {
            #pragma unroll
            for (int Mt = 0; Mt < 4; ++Mt) {
                f32x4 ee = (Mt == 0) ? e0 : (Mt == 1) ? e1 : (Mt == 2) ? e2 : e3;
                #pragma unroll
                for (int r = 0; r < 4; ++r) {
                    const int row = 16 * Mt + 4 * g + r;
                    *(float*)(slice + SIGO + row * 4) = fmaf(ee[r], 0.125f, b2v[0]);
                }
            }
        } else if (o < 33) {
            #pragma unroll
            for (int Mt = 0; Mt < 4; ++Mt) {
                f32x4 ee = (Mt == 0) ? e0 : (Mt == 1) ? e1 : (Mt == 2) ? e2 : e3;
                #pragma unroll
                for (int r = 0; r < 4; ++r) {
                    const float vv = fmaf(ee[r], 0.125f, b2v[Nt2]);
                    const float rr = sigmoid_f(vv) * 1.002f - 0.001f;
                    const int row = 16 * Mt + 4 * g + r;
                    *(__half*)(slice + row * 80 + (o - 1) * 2) = __float2half(rr);
                }
            }
        }
    }

    // ---- coalesced stores (nontemporal: keep L2 for the table) ----
    const int waveBase = blockIdx.x * TG + wv * 64;
    const int q0 = l & 3, r0 = l >> 2;
    #pragma unroll
    for (int q = 0; q < 4; ++q) {
        const int row = 16 * q + r0;
        i32x4 v = *(const i32x4*)(slice + row * 80 + q0 * 16);
        __builtin_nontemporal_store(v,
            (i32x4*)((char*)rgbW + (size_t)(waveBase + row) * 64 + q0 * 16));
    }
    const float sv = *(const float*)(slice + SIGO + l * 4);
    __builtin_nontemporal_store(sv, sigW + waveBase + l);
}

// ======================= split path: composite =======================
__global__ __launch_bounds__(512)
void k_comp(const __half* __restrict__ rgbW, const float* __restrict__ sigW,
            const float* __restrict__ depths, float* __restrict__ out)
{
    __shared__ float sgS[16 * SAMP];
    __shared__ float dpS[16 * SAMP];
    const int t = threadIdx.x;
    const int rayBase = blockIdx.x * 16;
    for (int i = t; i < 16 * SAMP; i += 512) {
        sgS[i] = sigW[(size_t)rayBase * SAMP + i];
        dpS[i] = depths[(size_t)rayBase * SAMP + i];
    }
    __syncthreads();

    const int rs = t >> 5;          // ray slot 0..15
    const int c = t & 31;           // channel
    const size_t mb = (size_t)(rayBase + rs) * SAMP;
    const ushort* rgbU = (const ushort*)rgbW;

    auto ldr = [&](size_t idx) -> float {
        ushort u = __builtin_nontemporal_load(rgbU + idx);
        __half h = *(__half*)&u;
        return __half2float(h);
    };

    float T = 1.f, a_out = 0.f;
    float sp = sgS[rs * SAMP], dp = dpS[rs * SAMP];
    float rp = ldr(mb * 32 + c);
    float rnx = ldr((mb + 1) * 32 + c);
    #pragma unroll 2
    for (int ss = 1; ss < SAMP; ++ss) {
        const float rc = rnx;
        const int nxt = (ss + 1 < SAMP) ? (ss + 1) : (SAMP - 1);
        rnx = ldr((mb + nxt) * 32 + c);
        const float sc = sgS[rs * SAMP + ss];
        const float dc = dpS[rs * SAMP + ss];
        const float dens = softplus_f(0.5f * (sp + sc) - 1.f);
        const float alpha = 1.f - __expf(-(dc - dp) * dens);
        a_out = fmaf(alpha * T, 0.5f * (rp + rc), a_out);
        T *= 1.f - alpha + 1e-10f;
        sp = sc; dp = dc; rp = rc;
    }
    out[(size_t)(rayBase + rs) * CF + c] = fmaf(a_out, 2.f, -1.f);
}

// ======================= fallback: round-2 fused kernel =======================
constexpr int THREADS = 384;
constexpr int SLICE = 9216;
constexpr int SIG_OFF = 5120;
constexpr int DEP_OFF = 5376;

template<bool USE_WS>
__global__ __launch_bounds__(THREADS)
void k_fused(const float* __restrict__ planes, const __half2* __restrict__ pt,
             const float* __restrict__ coords, const float* __restrict__ depths,
             const float* __restrict__ w1, const float* __restrict__ b1,
             const float* __restrict__ w2, const float* __restrict__ b2,
             float* __restrict__ out)
{
    __shared__ __align__(16) char sm[6 * SLICE];
    const int t = threadIdx.x;
    const int wv = t >> 6;
    const int l = t & 63;
    const int g = l >> 4;
    const int ln = l & 15;
    char* const slice = sm + wv * SLICE;

    const int msamp = blockIdx.x * THREADS + t;
    const int nb = (blockIdx.x >= (NB * RAYS / 4 / 2)) ? 1 : 0;

    f16x8 b1f[4];
    float b1v[4];
    #pragma unroll
    for (int Nt = 0; Nt < 4; ++Nt) {
        const int hn = 16 * Nt + ln;
        const float4* p0 = (const float4*)(w1 + hn * CF + g * 8);
        float4 u = p0[0], v = p0[1];
        b1f[Nt][0] = (_Float16)u.x; b1f[Nt][1] = (_Float16)u.y;
        b1f[Nt][2] = (_Float16)u.z; b1f[Nt][3] = (_Float16)u.w;
        b1f[Nt][4] = (_Float16)v.x; b1f[Nt][5] = (_Float16)v.y;
        b1f[Nt][6] = (_Float16)v.z; b1f[Nt][7] = (_Float16)v.w;
        b1v[Nt] = b1[hn];
    }
    f16x8 b2f[3][2];
    float b2v[3];
    #pragma unroll
    for (int Nt2 = 0; Nt2 < 3; ++Nt2) {
        const int o = 16 * Nt2 + ln;
        if (o < 33) {
            #pragma unroll
            for (int kh = 0; kh < 2; ++kh) {
                const float4* p0 = (const float4*)(w2 + o * HID + kh * 32 + g * 8);
                float4 u = p0[0], v = p0[1];
                b2f[Nt2][kh][0] = (_Float16)u.x; b2f[Nt2][kh][1] = (_Float16)u.y;
                b2f[Nt2][kh][2] = (_Float16)u.z; b2f[Nt2][kh][3] = (_Float16)u.w;
                b2f[Nt2][kh][4] = (_Float16)v.x; b2f[Nt2][kh][5] = (_Float16)v.y;
                b2f[Nt2][kh][6] = (_Float16)v.z; b2f[Nt2][kh][7] = (_Float16)v.w;
            }
            b2v[Nt2] = b2[o];
        } else {
            #pragma unroll
            for (int kh = 0; kh < 2; ++kh)
                #pragma unroll
                for (int i = 0; i < 8; ++i) b2f[Nt2][kh][i] = (_Float16)0.f;
            b2v[Nt2] = 0.f;
        }
    }

    const float* cp = coords + (size_t)msamp * 3;
    const float c0 = cp[0], c1 = cp[1], c2v = cp[2];
    const float myDep = depths[msamp];

    __half2 acc[16];
    #pragma unroll
    for (int k = 0; k < 16; ++k) acc[k] = __float2half2_rn(0.f);
    float xf32[CF];
    if constexpr (!USE_WS) {
        #pragma unroll
        for (int c = 0; c < CF; ++c) xf32[c] = 0.f;
    }

    #pragma unroll
    for (int p = 0; p < 3; ++p) {
        const float u = (p == 2) ? c2v : c0;
        const float v = (p == 0) ? c1 : ((p == 1) ? c2v : c0);
        const float xf = fmaf(u, 128.f, 127.5f);
        const float yf = fmaf(v, 128.f, 127.5f);
        const float x0f = floorf(xf), y0f = floorf(yf);
        const float wx = xf - x0f, wy = yf - y0f;
        const int x0 = (int)x0f, y0 = (int)y0f;
        const float vx0 = (x0 >= 0 && x0 < HW) ? 1.f : 0.f;
        const float vx1 = (x0 + 1 >= 0 && x0 + 1 < HW) ? 1.f : 0.f;
        const float vy0 = (y0 >= 0 && y0 < HW) ? 1.f : 0.f;
        const float vy1 = (y0 + 1 >= 0 && y0 + 1 < HW) ? 1.f : 0.f;
        const int xc0 = min(max(x0, 0), HW - 1), xc1 = min(max(x0 + 1, 0), HW - 1);
        const int yc0 = min(max(y0, 0), HW - 1), yc1 = min(max(y0 + 1, 0), HW - 1);
        const float w00 = (1.f - wx) * (1.f - wy) * vx0 * vy0;
        const float w10 = wx * (1.f - wy) * vx1 * vy0;
        const float w01 = (1.f - wx) * wy * vx0 * vy1;
        const float w11 = wx * wy * vx1 * vy1;

        if constexpr (USE_WS) {
            const __half2* pb = pt + ((size_t)(nb * 3 + p) << 16) * 16;
            auto tap = [&](int yc, int xc, float w) {
                const float4* tp = (const float4*)(pb + (size_t)(yc * HW + xc) * 16);
                const __half2 wh = __float2half2_rn(w);
                #pragma unroll
                for (int q = 0; q < 4; ++q) {
                    union { float4 f; __half2 h[4]; } u4;
                    u4.f = tp[q];
                    acc[q * 4 + 0] = __hfma2(wh, u4.h[0], acc[q * 4 + 0]);
                    acc[q * 4 + 1] = __hfma2(wh, u4.h[1], acc[q * 4 + 1]);
                    acc[q * 4 + 2] = __hfma2(wh, u4.h[2], acc[q * 4 + 2]);
                    acc[q * 4 + 3] = __hfma2(wh, u4.h[3], acc[q * 4 + 3]);
                }
            };
            tap(yc0, xc0, w00);
            tap(yc0, xc1, w10);
            tap(yc1, xc0, w01);
            tap(yc1, xc1, w11);
        } else {
            const float* pb = planes + (((size_t)(nb * 3 + p) * CF) << 16);
            const int i00 = yc0 * HW + xc0, i10 = yc0 * HW + xc1;
            const int i01 = yc1 * HW + xc0, i11 = yc1 * HW + xc1;
            #pragma unroll
            for (int c = 0; c < CF; ++c) {
                const float* pc = pb + ((size_t)c << 16);
                float a0 = fmaf(w00, pc[i00], fmaf(w10, pc[i10], 0.f));
                float a1 = fmaf(w01, pc[i01], fmaf(w11, pc[i11], 0.f));
                xf32[c] += a0 + a1;
            }
        }
    }
    if constexpr (!USE_WS) {
        #pragma unroll
        for (int k = 0; k < 16; ++k)
            acc[k] = __floats2half2_rn(xf32[2 * k], xf32[2 * k + 1]);
    }

    const __half2 third = __float2half2_rn(1.f / 3.f);
    #pragma unroll
    for (int c = 0; c < 4; ++c) {
        union { __half2 h[4]; i32x4 v; } u4;
        #pragma unroll
        for (int j = 0; j < 4; ++j) u4.h[j] = __hmul2(acc[4 * c + j], third);
        *(i32x4*)(slice + l * 80 + c * 16) = u4.v;
    }

    f16x8 a1[4];
    #pragma unroll
    for (int Mt = 0; Mt < 4; ++Mt)
        a1[Mt] = *(const f16x8*)(slice + (16 * Mt + ln) * 80 + g * 16);

    constexpr float is32 = 0.17677669529663687f;
    #pragma unroll
    for (int Nt = 0; Nt < 4; ++Nt) {
        f32x4 d0 = {0.f, 0.f, 0.f, 0.f};
        f32x4 d1 = {0.f, 0.f, 0.f, 0.f};
        f32x4 d2 = {0.f, 0.f, 0.f, 0.f};
        f32x4 d3 = {0.f, 0.f, 0.f, 0.f};
        d0 = __builtin_amdgcn_mfma_f32_16x16x32_f16(a1[0], b1f[Nt], d0, 0, 0, 0);
        d1 = __builtin_amdgcn_mfma_f32_16x16x32_f16(a1[1], b1f[Nt], d1, 0, 0, 0);
        d2 = __builtin_amdgcn_mfma_f32_16x16x32_f16(a1[2], b1f[Nt], d2, 0, 0, 0);
        d3 = __builtin_amdgcn_mfma_f32_16x16x32_f16(a1[3], b1f[Nt], d3, 0, 0, 0);
        const int hcol = 16 * Nt + ln;
        #pragma unroll
        for (int Mt = 0; Mt < 4; ++Mt) {
            f32x4 dd = (Mt == 0) ? d0 : (Mt == 1) ? d1 : (Mt == 2) ? d2 : d3;
            #pragma unroll
            for (int r = 0; r < 4; ++r) {
                const float hv = softplus_f(fmaf(dd[r], is32, b1v[Nt]));
                const int row = 16 * Mt + 4 * g + r;
                *(__half*)(slice + row * 144 + hcol * 2) = __float2half(hv);
            }
        }
    }

    f16x8 a2[4][2];
    #pragma unroll
    for (int Mt = 0; Mt < 4; ++Mt)
        #pragma unroll
        for (int kh = 0; kh < 2; ++kh)
            a2[Mt][kh] = *(const f16x8*)(slice + (16 * Mt + ln) * 144 + (kh * 4 + g) * 16);

    *(float*)(slice + DEP_OFF + l * 4) = myDep;

    #pragma unroll
    for (int Nt2 = 0; Nt2 < 3; ++Nt2) {
        f32x4 e0 = {0.f, 0.f, 0.f, 0.f};
        f32x4 e1 = {0.f, 0.f, 0.f, 0.f};
        f32x4 e2 = {0.f, 0.f, 0.f, 0.f};
        f32x4 e3 = {0.f, 0.f, 0.f, 0.f};
        #pragma unroll
        for (int kh = 0; kh < 2; ++kh) {
            e0 = __builtin_amdgcn_mfma_f32_16x16x32_f16(a2[0][kh], b2f[Nt2][kh], e0, 0, 0, 0);
            e1 = __builtin_amdgcn_mfma_f32_16x16x32_f16(a2[1][kh], b2f[Nt2][kh], e1, 0, 0, 0);
            e2 = __builtin_amdgcn_mfma_f32_16x16x32_f16(a2[2][kh], b2f[Nt2][kh], e2, 0, 0, 0);
            e3 = __builtin_amdgcn_mfma_f32_16x16x32_f16(a2[3][kh], b2f[Nt2][kh], e3, 0, 0, 0);
        }
        const int o = 16 * Nt2 + ln;
        if (o == 0) {
            #pragma unroll
            for (int Mt = 0; Mt < 4; ++Mt) {
                f32x4 ee = (Mt == 0) ? e0 : (Mt == 1) ? e1 : (Mt == 2) ? e2 : e3;
                #pragma unroll
                for (int r = 0; r < 4; ++r) {
                    const int row = 16 * Mt + 4 * g + r;
                    *(float*)(slice + SIG_OFF + row * 4) = fmaf(ee[r], 0.125f, b2v[0]);
                }
            }
        } else if (o < 33) {
            #pragma unroll
            for (int Mt = 0; Mt < 4; ++Mt) {
                f32x4 ee = (Mt == 0) ? e0 : (Mt == 1) ? e1 : (Mt == 2) ? e2 : e3;
                #pragma unroll
                for (int r = 0; r < 4; ++r) {
                    const float vv = fmaf(ee[r], 0.125f, b2v[Nt2]);
                    const float rr = sigmoid_f(vv) * 1.002f - 0.001f;
                    const int row = 16 * Mt + 4 * g + r;
                    *(__half*)(slice + row * 80 + (o + 1) * 2) = __float2half(rr);
                }
            }
        }
    }

    __syncthreads();

    if (t < 128) {
        const int crl = t >> 5;
        const int c = t & 31;
        const int bs = crl * SAMP;
        auto sigAt = [&](int sb) -> float {
            return *(const float*)(sm + (sb >> 6) * SLICE + SIG_OFF + (sb & 63) * 4);
        };
        auto depAt = [&](int sb) -> float {
            return *(const float*)(sm + (sb >> 6) * SLICE + DEP_OFF + (sb & 63) * 4);
        };
        auto rgbAt = [&](int sb) -> float {
            return __half2float(*(const __half*)(sm + (sb >> 6) * SLICE + (sb & 63) * 80 + (c + 1) * 2));
        };
        float T = 1.f, a_out = 0.f;
        float sp = sigAt(bs), dp = depAt(bs), rp = rgbAt(bs);
        for (int ss = 1; ss < SAMP; ++ss) {
            const float sc = sigAt(bs + ss);
            const float dc = depAt(bs + ss);
            const float rc = rgbAt(bs + ss);
            const float dens = softplus_f(0.5f * (sp + sc) - 1.f);
            const float alpha = 1.f - __expf(-(dc - dp) * dens);
            a_out = fmaf(alpha * T, 0.5f * (rp + rc), a_out);
            T *= 1.f - alpha + 1e-10f;
            sp = sc; dp = dc; rp = rc;
        }
        out[(size_t)(blockIdx.x * 4 + crl) * CF + c] = fmaf(a_out, 2.f, -1.f);
    }
}

extern "C" void kernel_launch(void* const* d_in, const int* in_sizes, int n_in,
                              void* d_out, int out_size, void* d_ws, size_t ws_size,
                              hipStream_t stream) {
    (void)in_sizes; (void)n_in; (void)out_size;
    const float* planes = (const float*)d_in[0];
    const float* coords = (const float*)d_in[1];
    const float* depths = (const float*)d_in[2];
    const float* w1 = (const float*)d_in[3];
    const float* b1 = (const float*)d_in[4];
    const float* w2 = (const float*)d_in[5];
    const float* b2 = (const float*)d_in[6];
    float* out = (float*)d_out;

    const size_t ptBytes  = (size_t)NB * 3 * HW * HW * CF * sizeof(__half);   // 25.2 MB
    const size_t rgbBytes = (size_t)M_TOTAL * CF * sizeof(__half);            // 50.3 MB
    const size_t sigBytes = (size_t)M_TOTAL * sizeof(float);                  //  3.1 MB
    const int tgrid = NB * 3 * HW * HW * CF / 2 / 256;                        // 24576

    if (ws_size >= ptBytes + rgbBytes + sigBytes) {
        __half2* pt = (__half2*)d_ws;
        __half* rgbW = (__half*)((char*)d_ws + ptBytes);
        float* sigW = (float*)((char*)d_ws + ptBytes + rgbBytes);
        k_transpose<<<tgrid, 256, 0, stream>>>(planes, pt);
        k_gmlp<<<M_TOTAL / TG, TG, 0, stream>>>(pt, coords, w1, b1, w2, b2, rgbW, sigW);
        k_comp<<<NB * RAYS / 16, 512, 0, stream>>>(rgbW, sigW, depths, out);
    } else if (ws_size >= ptBytes) {
        __half2* pt = (__half2*)d_ws;
        k_transpose<<<tgrid, 256, 0, stream>>>(planes, pt);
        k_fused<true><<<M_TOTAL / THREADS, THREADS, 0, stream>>>(planes, pt, coords, depths,
                                                                 w1, b1, w2, b2, out);
    } else {
        k_fused<false><<<M_TOTAL / THREADS, THREADS, 0, stream>>>(planes, nullptr, coords, depths,
                                                                  w1, b1, w2, b2, out);
    }
}

// Round 6
// 224.646 us; speedup vs baseline: 1.0669x; 1.0669x over previous
//
#include <hip/hip_runtime.h>
#include <hip/hip_fp16.h>

#define NB 2
#define RAYS 4096
#define SAMP 96
#define CF 32
#define HID 64
#define HW 256

constexpr int M_TOTAL = NB * RAYS * SAMP;   // 786432 samples

typedef _Float16 f16x8 __attribute__((ext_vector_type(8)));
typedef float f32x4 __attribute__((ext_vector_type(4)));
typedef int i32x4 __attribute__((ext_vector_type(4)));

__device__ __forceinline__ float softplus_f(float z) {
    return fmaxf(z, 0.f) + __logf(1.f + __expf(-fabsf(z)));
}
__device__ __forceinline__ float sigmoid_f(float z) {
    return __fdividef(1.f, 1.f + __expf(-z));
}

// planes (N,3,C,H,W) f32  ->  pt (N*3, H, W, C) f16  (channel-interleaved)
__global__ __launch_bounds__(256)
void k_transpose(const float* __restrict__ src, __half2* __restrict__ dst) {
    int i = blockIdx.x * 256 + threadIdx.x;   // over 6*65536*16 half2 outputs
    int c2 = i & 15;
    int xy = (i >> 4) & 0xFFFF;
    int pn = i >> 20;                          // n*3+p  in [0,6)
    const float* s = src + (((size_t)(pn * CF + c2 * 2)) << 16) + xy;
    float a = s[0];
    float b = s[(size_t)1 << 16];
    dst[((size_t)(pn) << 16) * 16 + (size_t)xy * 16 + c2] = __floats2half2_rn(a, b);
}

// ======================= split path: gather + MLP =======================
// 2-wave (128-thread) blocks, 18KiB LDS. NO min-occupancy clamp: round-5's
// __launch_bounds__(128,4) forced VGPR 116->64 and spilled ~150MB to scratch
// (WRITE_SIZE 52->141MB). Natural ~116 VGPR still allows 4 waves/SIMD.
constexpr int TG = 128;         // threads per gmlp block
constexpr int SLICE_A = 9216;   // per-wave LDS slice bytes
constexpr int SIGO = 5120;      // sigma region within slice (float[64])
// xS / rgb rows: row*80 (+ c*16 / + c*2);  hS rows: row*144

__global__ __launch_bounds__(TG)
void k_gmlp(const __half2* __restrict__ pt, const float* __restrict__ coords,
            const float* __restrict__ w1, const float* __restrict__ b1,
            const float* __restrict__ w2, const float* __restrict__ b2,
            __half* __restrict__ rgbW, float* __restrict__ sigW)
{
    __shared__ __align__(16) char sm[(TG / 64) * SLICE_A];
    const int t = threadIdx.x;
    const int wv = t >> 6;                 // wave id
    const int l = t & 63;
    const int g = l >> 4;
    const int ln = l & 15;
    char* const slice = sm + wv * SLICE_A;

    const int msamp = blockIdx.x * TG + t;
    const int nb = (msamp >= M_TOTAL / NB) ? 1 : 0;

    // ---- weight fragments in registers ----
    f16x8 b1f[4];
    float b1v[4];
    #pragma unroll
    for (int Nt = 0; Nt < 4; ++Nt) {
        const int hn = 16 * Nt + ln;
        const float4* p0 = (const float4*)(w1 + hn * CF + g * 8);
        float4 u = p0[0], v = p0[1];
        b1f[Nt][0] = (_Float16)u.x; b1f[Nt][1] = (_Float16)u.y;
        b1f[Nt][2] = (_Float16)u.z; b1f[Nt][3] = (_Float16)u.w;
        b1f[Nt][4] = (_Float16)v.x; b1f[Nt][5] = (_Float16)v.y;
        b1f[Nt][6] = (_Float16)v.z; b1f[Nt][7] = (_Float16)v.w;
        b1v[Nt] = b1[hn];
    }
    f16x8 b2f[3][2];
    float b2v[3];
    #pragma unroll
    for (int Nt2 = 0; Nt2 < 3; ++Nt2) {
        const int o = 16 * Nt2 + ln;
        if (o < 33) {
            #pragma unroll
            for (int kh = 0; kh < 2; ++kh) {
                const float4* p0 = (const float4*)(w2 + o * HID + kh * 32 + g * 8);
                float4 u = p0[0], v = p0[1];
                b2f[Nt2][kh][0] = (_Float16)u.x; b2f[Nt2][kh][1] = (_Float16)u.y;
                b2f[Nt2][kh][2] = (_Float16)u.z; b2f[Nt2][kh][3] = (_Float16)u.w;
                b2f[Nt2][kh][4] = (_Float16)v.x; b2f[Nt2][kh][5] = (_Float16)v.y;
                b2f[Nt2][kh][6] = (_Float16)v.z; b2f[Nt2][kh][7] = (_Float16)v.w;
            }
            b2v[Nt2] = b2[o];
        } else {
            #pragma unroll
            for (int kh = 0; kh < 2; ++kh)
                #pragma unroll
                for (int i = 0; i < 8; ++i) b2f[Nt2][kh][i] = (_Float16)0.f;
            b2v[Nt2] = 0.f;
        }
    }

    // ---- gather ----
    const float* cp = coords + (size_t)msamp * 3;
    const float c0 = cp[0], c1 = cp[1], c2v = cp[2];

    __half2 acc[16];
    #pragma unroll
    for (int k = 0; k < 16; ++k) acc[k] = __float2half2_rn(0.f);

    #pragma unroll
    for (int p = 0; p < 3; ++p) {
        const float u = (p == 2) ? c2v : c0;
        const float v = (p == 0) ? c1 : ((p == 1) ? c2v : c0);
        const float xf = fmaf(u, 128.f, 127.5f);
        const float yf = fmaf(v, 128.f, 127.5f);
        const float x0f = floorf(xf), y0f = floorf(yf);
        const float wx = xf - x0f, wy = yf - y0f;
        const int x0 = (int)x0f, y0 = (int)y0f;
        const float vx0 = (x0 >= 0 && x0 < HW) ? 1.f : 0.f;
        const float vx1 = (x0 + 1 >= 0 && x0 + 1 < HW) ? 1.f : 0.f;
        const float vy0 = (y0 >= 0 && y0 < HW) ? 1.f : 0.f;
        const float vy1 = (y0 + 1 >= 0 && y0 + 1 < HW) ? 1.f : 0.f;
        const int xc0 = min(max(x0, 0), HW - 1), xc1 = min(max(x0 + 1, 0), HW - 1);
        const int yc0 = min(max(y0, 0), HW - 1), yc1 = min(max(y0 + 1, 0), HW - 1);
        const float w00 = (1.f - wx) * (1.f - wy) * vx0 * vy0;
        const float w10 = wx * (1.f - wy) * vx1 * vy0;
        const float w01 = (1.f - wx) * wy * vx0 * vy1;
        const float w11 = wx * wy * vx1 * vy1;

        const __half2* pb = pt + ((size_t)(nb * 3 + p) << 16) * 16;
        auto tap = [&](int yc, int xc, float w) {
            const float4* tp = (const float4*)(pb + (size_t)(yc * HW + xc) * 16);
            const __half2 wh = __float2half2_rn(w);
            #pragma unroll
            for (int q = 0; q < 4; ++q) {
                union { float4 f; __half2 h[4]; } u4;
                u4.f = tp[q];
                acc[q * 4 + 0] = __hfma2(wh, u4.h[0], acc[q * 4 + 0]);
                acc[q * 4 + 1] = __hfma2(wh, u4.h[1], acc[q * 4 + 1]);
                acc[q * 4 + 2] = __hfma2(wh, u4.h[2], acc[q * 4 + 2]);
                acc[q * 4 + 3] = __hfma2(wh, u4.h[3], acc[q * 4 + 3]);
            }
        };
        tap(yc0, xc0, w00);
        tap(yc0, xc1, w10);
        tap(yc1, xc0, w01);
        tap(yc1, xc1, w11);
    }

    // ---- stage x ----
    const __half2 third = __float2half2_rn(1.f / 3.f);
    #pragma unroll
    for (int c = 0; c < 4; ++c) {
        union { __half2 h[4]; i32x4 v; } u4;
        #pragma unroll
        for (int j = 0; j < 4; ++j) u4.h[j] = __hmul2(acc[4 * c + j], third);
        *(i32x4*)(slice + l * 80 + c * 16) = u4.v;
    }

    // ---- layer 1 ----
    f16x8 a1[4];
    #pragma unroll
    for (int Mt = 0; Mt < 4; ++Mt)
        a1[Mt] = *(const f16x8*)(slice + (16 * Mt + ln) * 80 + g * 16);

    constexpr float is32 = 0.17677669529663687f;
    #pragma unroll
    for (int Nt = 0; Nt < 4; ++Nt) {
        f32x4 d0 = {0.f, 0.f, 0.f, 0.f};
        f32x4 d1 = {0.f, 0.f, 0.f, 0.f};
        f32x4 d2 = {0.f, 0.f, 0.f, 0.f};
        f32x4 d3 = {0.f, 0.f, 0.f, 0.f};
        d0 = __builtin_amdgcn_mfma_f32_16x16x32_f16(a1[0], b1f[Nt], d0, 0, 0, 0);
        d1 = __builtin_amdgcn_mfma_f32_16x16x32_f16(a1[1], b1f[Nt], d1, 0, 0, 0);
        d2 = __builtin_amdgcn_mfma_f32_16x16x32_f16(a1[2], b1f[Nt], d2, 0, 0, 0);
        d3 = __builtin_amdgcn_mfma_f32_16x16x32_f16(a1[3], b1f[Nt], d3, 0, 0, 0);
        const int hcol = 16 * Nt + ln;
        #pragma unroll
        for (int Mt = 0; Mt < 4; ++Mt) {
            f32x4 dd = (Mt == 0) ? d0 : (Mt == 1) ? d1 : (Mt == 2) ? d2 : d3;
            #pragma unroll
            for (int r = 0; r < 4; ++r) {
                const float hv = softplus_f(fmaf(dd[r], is32, b1v[Nt]));
                const int row = 16 * Mt + 4 * g + r;
                *(__half*)(slice + row * 144 + hcol * 2) = __float2half(hv);
            }
        }
    }

    // ---- layer 2 ----
    f16x8 a2[4][2];
    #pragma unroll
    for (int Mt = 0; Mt < 4; ++Mt)
        #pragma unroll
        for (int kh = 0; kh < 2; ++kh)
            a2[Mt][kh] = *(const f16x8*)(slice + (16 * Mt + ln) * 144 + (kh * 4 + g) * 16);

    #pragma unroll
    for (int Nt2 = 0; Nt2 < 3; ++Nt2) {
        f32x4 e0 = {0.f, 0.f, 0.f, 0.f};
        f32x4 e1 = {0.f, 0.f, 0.f, 0.f};
        f32x4 e2 = {0.f, 0.f, 0.f, 0.f};
        f32x4 e3 = {0.f, 0.f, 0.f, 0.f};
        #pragma unroll
        for (int kh = 0; kh < 2; ++kh) {
            e0 = __builtin_amdgcn_mfma_f32_16x16x32_f16(a2[0][kh], b2f[Nt2][kh], e0, 0, 0, 0);
            e1 = __builtin_amdgcn_mfma_f32_16x16x32_f16(a2[1][kh], b2f[Nt2][kh], e1, 0, 0, 0);
            e2 = __builtin_amdgcn_mfma_f32_16x16x32_f16(a2[2][kh], b2f[Nt2][kh], e2, 0, 0, 0);
            e3 = __builtin_amdgcn_mfma_f32_16x16x32_f16(a2[3][kh], b2f[Nt2][kh], e3, 0, 0, 0);
        }
        const int o = 16 * Nt2 + ln;
        if (o == 0) {
            #pragma unroll
            for (int Mt = 0; Mt < 4; ++Mt) {
                f32x4 ee = (Mt == 0) ? e0 : (Mt == 1) ? e1 : (Mt == 2) ? e2 : e3;
                #pragma unroll
                for (int r = 0; r < 4; ++r) {
                    const int row = 16 * Mt + 4 * g + r;
                    *(float*)(slice + SIGO + row * 4) = fmaf(ee[r], 0.125f, b2v[0]);
                }
            }
        } else if (o < 33) {
            #pragma unroll
            for (int Mt = 0; Mt < 4; ++Mt) {
                f32x4 ee = (Mt == 0) ? e0 : (Mt == 1) ? e1 : (Mt == 2) ? e2 : e3;
                #pragma unroll
                for (int r = 0; r < 4; ++r) {
                    const float vv = fmaf(ee[r], 0.125f, b2v[Nt2]);
                    const float rr = sigmoid_f(vv) * 1.002f - 0.001f;
                    const int row = 16 * Mt + 4 * g + r;
                    *(__half*)(slice + row * 80 + (o - 1) * 2) = __float2half(rr);
                }
            }
        }
    }

    // ---- coalesced stores (nontemporal: keep L2 for the table) ----
    const int waveBase = blockIdx.x * TG + wv * 64;
    const int q0 = l & 3, r0 = l >> 2;
    #pragma unroll
    for (int q = 0; q < 4; ++q) {
        const int row = 16 * q + r0;
        i32x4 v = *(const i32x4*)(slice + row * 80 + q0 * 16);
        __builtin_nontemporal_store(v,
            (i32x4*)((char*)rgbW + (size_t)(waveBase + row) * 64 + q0 * 16));
    }
    const float sv = *(const float*)(slice + SIGO + l * 4);
    __builtin_nontemporal_store(sv, sigW + waveBase + l);
}

// ======================= split path: composite =======================
__global__ __launch_bounds__(512)
void k_comp(const __half* __restrict__ rgbW, const float* __restrict__ sigW,
            const float* __restrict__ depths, float* __restrict__ out)
{
    __shared__ float sgS[16 * SAMP];
    __shared__ float dpS[16 * SAMP];
    const int t = threadIdx.x;
    const int rayBase = blockIdx.x * 16;
    for (int i = t; i < 16 * SAMP; i += 512) {
        sgS[i] = sigW[(size_t)rayBase * SAMP + i];
        dpS[i] = depths[(size_t)rayBase * SAMP + i];
    }
    __syncthreads();

    const int rs = t >> 5;          // ray slot 0..15
    const int c = t & 31;           // channel
    const size_t mb = (size_t)(rayBase + rs) * SAMP;
    const ushort* rgbU = (const ushort*)rgbW;

    auto ldr = [&](size_t idx) -> float {
        ushort u = __builtin_nontemporal_load(rgbU + idx);
        __half h = *(__half*)&u;
        return __half2float(h);
    };

    float T = 1.f, a_out = 0.f;
    float sp = sgS[rs * SAMP], dp = dpS[rs * SAMP];
    float rp = ldr(mb * 32 + c);
    float rnx = ldr((mb + 1) * 32 + c);
    #pragma unroll 2
    for (int ss = 1; ss < SAMP; ++ss) {
        const float rc = rnx;
        const int nxt = (ss + 1 < SAMP) ? (ss + 1) : (SAMP - 1);
        rnx = ldr((mb + nxt) * 32 + c);
        const float sc = sgS[rs * SAMP + ss];
        const float dc = dpS[rs * SAMP + ss];
        const float dens = softplus_f(0.5f * (sp + sc) - 1.f);
        const float alpha = 1.f - __expf(-(dc - dp) * dens);
        a_out = fmaf(alpha * T, 0.5f * (rp + rc), a_out);
        T *= 1.f - alpha + 1e-10f;
        sp = sc; dp = dc; rp = rc;
    }
    out[(size_t)(rayBase + rs) * CF + c] = fmaf(a_out, 2.f, -1.f);
}

// ======================= fallback: round-2 fused kernel =======================
constexpr int THREADS = 384;
constexpr int SLICE = 9216;
constexpr int SIG_OFF = 5120;
constexpr int DEP_OFF = 5376;

template<bool USE_WS>
__global__ __launch_bounds__(THREADS)
void k_fused(const float* __restrict__ planes, const __half2* __restrict__ pt,
             const float* __restrict__ coords, const float* __restrict__ depths,
             const float* __restrict__ w1, const float* __restrict__ b1,
             const float* __restrict__ w2, const float* __restrict__ b2,
             float* __restrict__ out)
{
    __shared__ __align__(16) char sm[6 * SLICE];
    const int t = threadIdx.x;
    const int wv = t >> 6;
    const int l = t & 63;
    const int g = l >> 4;
    const int ln = l & 15;
    char* const slice = sm + wv * SLICE;

    const int msamp = blockIdx.x * THREADS + t;
    const int nb = (blockIdx.x >= (NB * RAYS / 4 / 2)) ? 1 : 0;

    f16x8 b1f[4];
    float b1v[4];
    #pragma unroll
    for (int Nt = 0; Nt < 4; ++Nt) {
        const int hn = 16 * Nt + ln;
        const float4* p0 = (const float4*)(w1 + hn * CF + g * 8);
        float4 u = p0[0], v = p0[1];
        b1f[Nt][0] = (_Float16)u.x; b1f[Nt][1] = (_Float16)u.y;
        b1f[Nt][2] = (_Float16)u.z; b1f[Nt][3] = (_Float16)u.w;
        b1f[Nt][4] = (_Float16)v.x; b1f[Nt][5] = (_Float16)v.y;
        b1f[Nt][6] = (_Float16)v.z; b1f[Nt][7] = (_Float16)v.w;
        b1v[Nt] = b1[hn];
    }
    f16x8 b2f[3][2];
    float b2v[3];
    #pragma unroll
    for (int Nt2 = 0; Nt2 < 3; ++Nt2) {
        const int o = 16 * Nt2 + ln;
        if (o < 33) {
            #pragma unroll
            for (int kh = 0; kh < 2; ++kh) {
                const float4* p0 = (const float4*)(w2 + o * HID + kh * 32 + g * 8);
                float4 u = p0[0], v = p0[1];
                b2f[Nt2][kh][0] = (_Float16)u.x; b2f[Nt2][kh][1] = (_Float16)u.y;
                b2f[Nt2][kh][2] = (_Float16)u.z; b2f[Nt2][kh][3] = (_Float16)u.w;
                b2f[Nt2][kh][4] = (_Float16)v.x; b2f[Nt2][kh][5] = (_Float16)v.y;
                b2f[Nt2][kh][6] = (_Float16)v.z; b2f[Nt2][kh][7] = (_Float16)v.w;
            }
            b2v[Nt2] = b2[o];
        } else {
            #pragma unroll
            for (int kh = 0; kh < 2; ++kh)
                #pragma unroll
                for (int i = 0; i < 8; ++i) b2f[Nt2][kh][i] = (_Float16)0.f;
            b2v[Nt2] = 0.f;
        }
    }

    const float* cp = coords + (size_t)msamp * 3;
    const float c0 = cp[0], c1 = cp[1], c2v = cp[2];
    const float myDep = depths[msamp];

    __half2 acc[16];
    #pragma unroll
    for (int k = 0; k < 16; ++k) acc[k] = __float2half2_rn(0.f);
    float xf32[CF];
    if constexpr (!USE_WS) {
        #pragma unroll
        for (int c = 0; c < CF; ++c) xf32[c] = 0.f;
    }

    #pragma unroll
    for (int p = 0; p < 3; ++p) {
        const float u = (p == 2) ? c2v : c0;
        const float v = (p == 0) ? c1 : ((p == 1) ? c2v : c0);
        const float xf = fmaf(u, 128.f, 127.5f);
        const float yf = fmaf(v, 128.f, 127.5f);
        const float x0f = floorf(xf), y0f = floorf(yf);
        const float wx = xf - x0f, wy = yf - y0f;
        const int x0 = (int)x0f, y0 = (int)y0f;
        const float vx0 = (x0 >= 0 && x0 < HW) ? 1.f : 0.f;
        const float vx1 = (x0 + 1 >= 0 && x0 + 1 < HW) ? 1.f : 0.f;
        const float vy0 = (y0 >= 0 && y0 < HW) ? 1.f : 0.f;
        const float vy1 = (y0 + 1 >= 0 && y0 + 1 < HW) ? 1.f : 0.f;
        const int xc0 = min(max(x0, 0), HW - 1), xc1 = min(max(x0 + 1, 0), HW - 1);
        const int yc0 = min(max(y0, 0), HW - 1), yc1 = min(max(y0 + 1, 0), HW - 1);
        const float w00 = (1.f - wx) * (1.f - wy) * vx0 * vy0;
        const float w10 = wx * (1.f - wy) * vx1 * vy0;
        const float w01 = (1.f - wx) * wy * vx0 * vy1;
        const float w11 = wx * wy * vx1 * vy1;

        if constexpr (USE_WS) {
            const __half2* pb = pt + ((size_t)(nb * 3 + p) << 16) * 16;
            auto tap = [&](int yc, int xc, float w) {
                const float4* tp = (const float4*)(pb + (size_t)(yc * HW + xc) * 16);
                const __half2 wh = __float2half2_rn(w);
                #pragma unroll
                for (int q = 0; q < 4; ++q) {
                    union { float4 f; __half2 h[4]; } u4;
                    u4.f = tp[q];
                    acc[q * 4 + 0] = __hfma2(wh, u4.h[0], acc[q * 4 + 0]);
                    acc[q * 4 + 1] = __hfma2(wh, u4.h[1], acc[q * 4 + 1]);
                    acc[q * 4 + 2] = __hfma2(wh, u4.h[2], acc[q * 4 + 2]);
                    acc[q * 4 + 3] = __hfma2(wh, u4.h[3], acc[q * 4 + 3]);
                }
            };
            tap(yc0, xc0, w00);
            tap(yc0, xc1, w10);
            tap(yc1, xc0, w01);
            tap(yc1, xc1, w11);
        } else {
            const float* pb = planes + (((size_t)(nb * 3 + p) * CF) << 16);
            const int i00 = yc0 * HW + xc0, i10 = yc0 * HW + xc1;
            const int i01 = yc1 * HW + xc0, i11 = yc1 * HW + xc1;
            #pragma unroll
            for (int c = 0; c < CF; ++c) {
                const float* pc = pb + ((size_t)c << 16);
                float a0 = fmaf(w00, pc[i00], fmaf(w10, pc[i10], 0.f));
                float a1 = fmaf(w01, pc[i01], fmaf(w11, pc[i11], 0.f));
                xf32[c] += a0 + a1;
            }
        }
    }
    if constexpr (!USE_WS) {
        #pragma unroll
        for (int k = 0; k < 16; ++k)
            acc[k] = __floats2half2_rn(xf32[2 * k], xf32[2 * k + 1]);
    }

    const __half2 third = __float2half2_rn(1.f / 3.f);
    #pragma unroll
    for (int c = 0; c < 4; ++c) {
        union { __half2 h[4]; i32x4 v; } u4;
        #pragma unroll
        for (int j = 0; j < 4; ++j) u4.h[j] = __hmul2(acc[4 * c + j], third);
        *(i32x4*)(slice + l * 80 + c * 16) = u4.v;
    }

    f16x8 a1[4];
    #pragma unroll
    for (int Mt = 0; Mt < 4; ++Mt)
        a1[Mt] = *(const f16x8*)(slice + (16 * Mt + ln) * 80 + g * 16);

    constexpr float is32 = 0.17677669529663687f;
    #pragma unroll
    for (int Nt = 0; Nt < 4; ++Nt) {
        f32x4 d0 = {0.f, 0.f, 0.f, 0.f};
        f32x4 d1 = {0.f, 0.f, 0.f, 0.f};
        f32x4 d2 = {0.f, 0.f, 0.f, 0.f};
        f32x4 d3 = {0.f, 0.f, 0.f, 0.f};
        d0 = __builtin_amdgcn_mfma_f32_16x16x32_f16(a1[0], b1f[Nt], d0, 0, 0, 0);
        d1 = __builtin_amdgcn_mfma_f32_16x16x32_f16(a1[1], b1f[Nt], d1, 0, 0, 0);
        d2 = __builtin_amdgcn_mfma_f32_16x16x32_f16(a1[2], b1f[Nt], d2, 0, 0, 0);
        d3 = __builtin_amdgcn_mfma_f32_16x16x32_f16(a1[3], b1f[Nt], d3, 0, 0, 0);
        const int hcol = 16 * Nt + ln;
        #pragma unroll
        for (int Mt = 0; Mt < 4; ++Mt) {
            f32x4 dd = (Mt == 0) ? d0 : (Mt == 1) ? d1 : (Mt == 2) ? d2 : d3;
            #pragma unroll
            for (int r = 0; r < 4; ++r) {
                const float hv = softplus_f(fmaf(dd[r], is32, b1v[Nt]));
                const int row = 16 * Mt + 4 * g + r;
                *(__half*)(slice + row * 144 + hcol * 2) = __float2half(hv);
            }
        }
    }

    f16x8 a2[4][2];
    #pragma unroll
    for (int Mt = 0; Mt < 4; ++Mt)
        #pragma unroll
        for (int kh = 0; kh < 2; ++kh)
            a2[Mt][kh] = *(const f16x8*)(slice + (16 * Mt + ln) * 144 + (kh * 4 + g) * 16);

    *(float*)(slice + DEP_OFF + l * 4) = myDep;

    #pragma unroll
    for (int Nt2 = 0; Nt2 < 3; ++Nt2) {
        f32x4 e0 = {0.f, 0.f, 0.f, 0.f};
        f32x4 e1 = {0.f, 0.f, 0.f, 0.f};
        f32x4 e2 = {0.f, 0.f, 0.f, 0.f};
        f32x4 e3 = {0.f, 0.f, 0.f, 0.f};
        #pragma unroll
        for (int kh = 0; kh < 2; ++kh) {
            e0 = __builtin_amdgcn_mfma_f32_16x16x32_f16(a2[0][kh], b2f[Nt2][kh], e0, 0, 0, 0);
            e1 = __builtin_amdgcn_mfma_f32_16x16x32_f16(a2[1][kh], b2f[Nt2][kh], e1, 0, 0, 0);
            e2 = __builtin_amdgcn_mfma_f32_16x16x32_f16(a2[2][kh], b2f[Nt2][kh], e2, 0, 0, 0);
            e3 = __builtin_amdgcn_mfma_f32_16x16x32_f16(a2[3][kh], b2f[Nt2][kh], e3, 0, 0, 0);
        }
        const int o = 16 * Nt2 + ln;
        if (o == 0) {
            #pragma unroll
            for (int Mt = 0; Mt < 4; ++Mt) {
                f32x4 ee = (Mt == 0) ? e0 : (Mt == 1) ? e1 : (Mt == 2) ? e2 : e3;
                #pragma unroll
                for (int r = 0; r < 4; ++r) {
                    const int row = 16 * Mt + 4 * g + r;
                    *(float*)(slice + SIG_OFF + row * 4) = fmaf(ee[r], 0.125f, b2v[0]);
                }
            }
        } else if (o < 33) {
            #pragma unroll
            for (int Mt = 0; Mt < 4; ++Mt) {
                f32x4 ee = (Mt == 0) ? e0 : (Mt == 1) ? e1 : (Mt == 2) ? e2 : e3;
                #pragma unroll
                for (int r = 0; r < 4; ++r) {
                    const float vv = fmaf(ee[r], 0.125f, b2v[Nt2]);
                    const float rr = sigmoid_f(vv) * 1.002f - 0.001f;
                    const int row = 16 * Mt + 4 * g + r;
                    *(__half*)(slice + row * 80 + (o + 1) * 2) = __float2half(rr);
                }
            }
        }
    }

    __syncthreads();

    if (t < 128) {
        const int crl = t >> 5;
        const int c = t & 31;
        const int bs = crl * SAMP;
        auto sigAt = [&](int sb) -> float {
            return *(const float*)(sm + (sb >> 6) * SLICE + SIG_OFF + (sb & 63) * 4);
        };
        auto depAt = [&](int sb) -> float {
            return *(const float*)(sm + (sb >> 6) * SLICE + DEP_OFF + (sb & 63) * 4);
        };
        auto rgbAt = [&](int sb) -> float {
            return __half2float(*(const __half*)(sm + (sb >> 6) * SLICE + (sb & 63) * 80 + (c + 1) * 2));
        };
        float T = 1.f, a_out = 0.f;
        float sp = sigAt(bs), dp = depAt(bs), rp = rgbAt(bs);
        for (int ss = 1; ss < SAMP; ++ss) {
            const float sc = sigAt(bs + ss);
            const float dc = depAt(bs + ss);
            const float rc = rgbAt(bs + ss);
            const float dens = softplus_f(0.5f * (sp + sc) - 1.f);
            const float alpha = 1.f - __expf(-(dc - dp) * dens);
            a_out = fmaf(alpha * T, 0.5f * (rp + rc), a_out);
            T *= 1.f - alpha + 1e-10f;
            sp = sc; dp = dc; rp = rc;
        }
        out[(size_t)(blockIdx.x * 4 + crl) * CF + c] = fmaf(a_out, 2.f, -1.f);
    }
}

extern "C" void kernel_launch(void* const* d_in, const int* in_sizes, int n_in,
                              void* d_out, int out_size, void* d_ws, size_t ws_size,
                              hipStream_t stream) {
    (void)in_sizes; (void)n_in; (void)out_size;
    const float* planes = (const float*)d_in[0];
    const float* coords = (const float*)d_in[1];
    const float* depths = (const float*)d_in[2];
    const float* w1 = (const float*)d_in[3];
    const float* b1 = (const float*)d_in[4];
    const float* w2 = (const float*)d_in[5];
    const float* b2 = (const float*)d_in[6];
    float* out = (float*)d_out;

    const size_t ptBytes  = (size_t)NB * 3 * HW * HW * CF * sizeof(__half);   // 25.2 MB
    const size_t rgbBytes = (size_t)M_TOTAL * CF * sizeof(__half);            // 50.3 MB
    const size_t sigBytes = (size_t)M_TOTAL * sizeof(float);                  //  3.1 MB
    const int tgrid = NB * 3 * HW * HW * CF / 2 / 256;                        // 24576

    if (ws_size >= ptBytes + rgbBytes + sigBytes) {
        __half2* pt = (__half2*)d_ws;
        __half* rgbW = (__half*)((char*)d_ws + ptBytes);
        float* sigW = (float*)((char*)d_ws + ptBytes + rgbBytes);
        k_transpose<<<tgrid, 256, 0, stream>>>(planes, pt);
        k_gmlp<<<M_TOTAL / TG, TG, 0, stream>>>(pt, coords, w1, b1, w2, b2, rgbW, sigW);
        k_comp<<<NB * RAYS / 16, 512, 0, stream>>>(rgbW, sigW, depths, out);
    } else if (ws_size >= ptBytes) {
        __half2* pt = (__half2*)d_ws;
        k_transpose<<<tgrid, 256, 0, stream>>>(planes, pt);
        k_fused<true><<<M_TOTAL / THREADS, THREADS, 0, stream>>>(planes, pt, coords, depths,
                                                                 w1, b1, w2, b2, out);
    } else {
        k_fused<false><<<M_TOTAL / THREADS, THREADS, 0, stream>>>(planes, nullptr, coords, depths,
                                                                  w1, b1, w2, b2, out);
    }
}

// Round 7
// 188.911 us; speedup vs baseline: 1.2687x; 1.1892x over previous
//
#include <hip/hip_runtime.h>
#include <hip/hip_fp16.h>

#define NB 2
#define RAYS 4096
#define SAMP 96
#define CF 32
#define HID 64
#define HW 256

constexpr int M_TOTAL = NB * RAYS * SAMP;   // 786432 samples

typedef _Float16 f16x8 __attribute__((ext_vector_type(8)));
typedef float f32x4 __attribute__((ext_vector_type(4)));
typedef int i32x4 __attribute__((ext_vector_type(4)));

__device__ __forceinline__ float softplus_f(float z) {
    return fmaxf(z, 0.f) + __logf(1.f + __expf(-fabsf(z)));
}
__device__ __forceinline__ float sigmoid_f(float z) {
    return __fdividef(1.f, 1.f + __expf(-z));
}

// planes (N,3,C,H,W) f32  ->  pt (N*3, H, W, C) f16  (channel-interleaved)
__global__ __launch_bounds__(256)
void k_transpose(const float* __restrict__ src, __half2* __restrict__ dst) {
    int i = blockIdx.x * 256 + threadIdx.x;   // over 6*65536*16 half2 outputs
    int c2 = i & 15;
    int xy = (i >> 4) & 0xFFFF;
    int pn = i >> 20;                          // n*3+p  in [0,6)
    const float* s = src + (((size_t)(pn * CF + c2 * 2)) << 16) + xy;
    float a = s[0];
    float b = s[(size_t)1 << 16];
    dst[((size_t)(pn) << 16) * 16 + (size_t)xy * 16 + c2] = __floats2half2_rn(a, b);
}

// ======================= split path: gather + MLP =======================
// 2-wave (128-thread) blocks, 18KiB LDS, natural VGPR (no min-occ clamp:
// r5 showed __launch_bounds__(128,4) forces 64 VGPR + 150MB spill traffic).
// Gather is 4-lane cooperative: tap row = 64B = 4 lanes x 16B, and lane
// (g,ln) owning channels 8g..8g+7 of sample 16*Mt+ln IS the MFMA A-fragment
// layout -> fragments built directly in registers, 4x fewer L1 line-probes.
constexpr int TG = 128;         // threads per gmlp block
constexpr int SLICE_A = 9216;   // per-wave LDS slice bytes
constexpr int SIGO = 5120;      // sigma region within slice (float[64])
// rgb rows: row*80 + o*2;  hS rows: row*144 (overlaps, sequenced by reg frags)

__global__ __launch_bounds__(TG)
void k_gmlp(const __half2* __restrict__ pt, const float* __restrict__ coords,
            const float* __restrict__ w1, const float* __restrict__ b1,
            const float* __restrict__ w2, const float* __restrict__ b2,
            __half* __restrict__ rgbW, float* __restrict__ sigW)
{
    __shared__ __align__(16) char sm[(TG / 64) * SLICE_A];
    const int t = threadIdx.x;
    const int wv = t >> 6;                 // wave id
    const int l = t & 63;
    const int g = l >> 4;
    const int ln = l & 15;
    char* const slice = sm + wv * SLICE_A;

    // ---- weight fragments in registers ----
    f16x8 b1f[4];
    float b1v[4];
    #pragma unroll
    for (int Nt = 0; Nt < 4; ++Nt) {
        const int hn = 16 * Nt + ln;
        const float4* p0 = (const float4*)(w1 + hn * CF + g * 8);
        float4 u = p0[0], v = p0[1];
        b1f[Nt][0] = (_Float16)u.x; b1f[Nt][1] = (_Float16)u.y;
        b1f[Nt][2] = (_Float16)u.z; b1f[Nt][3] = (_Float16)u.w;
        b1f[Nt][4] = (_Float16)v.x; b1f[Nt][5] = (_Float16)v.y;
        b1f[Nt][6] = (_Float16)v.z; b1f[Nt][7] = (_Float16)v.w;
        b1v[Nt] = b1[hn];
    }
    f16x8 b2f[3][2];
    float b2v[3];
    #pragma unroll
    for (int Nt2 = 0; Nt2 < 3; ++Nt2) {
        const int o = 16 * Nt2 + ln;
        if (o < 33) {
            #pragma unroll
            for (int kh = 0; kh < 2; ++kh) {
                const float4* p0 = (const float4*)(w2 + o * HID + kh * 32 + g * 8);
                float4 u = p0[0], v = p0[1];
                b2f[Nt2][kh][0] = (_Float16)u.x; b2f[Nt2][kh][1] = (_Float16)u.y;
                b2f[Nt2][kh][2] = (_Float16)u.z; b2f[Nt2][kh][3] = (_Float16)u.w;
                b2f[Nt2][kh][4] = (_Float16)v.x; b2f[Nt2][kh][5] = (_Float16)v.y;
                b2f[Nt2][kh][6] = (_Float16)v.z; b2f[Nt2][kh][7] = (_Float16)v.w;
            }
            b2v[Nt2] = b2[o];
        } else {
            #pragma unroll
            for (int kh = 0; kh < 2; ++kh)
                #pragma unroll
                for (int i = 0; i < 8; ++i) b2f[Nt2][kh][i] = (_Float16)0.f;
            b2v[Nt2] = 0.f;
        }
    }

    // ---- gather: 4-lane-coalesced taps, A-fragments built in registers ----
    const int waveBaseS = blockIdx.x * TG + wv * 64;
    const int nb = (waveBaseS >= M_TOTAL / NB) ? 1 : 0;
    const __half2* pt_nb = pt + (((size_t)nb * 3) << 16) * 16;
    const __half2 third = __float2half2_rn(1.f / 3.f);

    f16x8 a1[4];
    #pragma unroll
    for (int Mt = 0; Mt < 4; ++Mt) {
        const int smp = waveBaseS + 16 * Mt + ln;
        const float* cp = coords + (size_t)smp * 3;
        const float c0 = cp[0], c1 = cp[1], c2v = cp[2];
        __half2 acc4[4];
        #pragma unroll
        for (int j = 0; j < 4; ++j) acc4[j] = __float2half2_rn(0.f);

        #pragma unroll
        for (int p = 0; p < 3; ++p) {
            const float u = (p == 2) ? c2v : c0;
            const float v = (p == 0) ? c1 : ((p == 1) ? c2v : c0);
            const float xf = fmaf(u, 128.f, 127.5f);
            const float yf = fmaf(v, 128.f, 127.5f);
            const float x0f = floorf(xf), y0f = floorf(yf);
            const float wx = xf - x0f, wy = yf - y0f;
            const int x0 = (int)x0f, y0 = (int)y0f;
            const float vx0 = (x0 >= 0 && x0 < HW) ? 1.f : 0.f;
            const float vx1 = (x0 + 1 >= 0 && x0 + 1 < HW) ? 1.f : 0.f;
            const float vy0 = (y0 >= 0 && y0 < HW) ? 1.f : 0.f;
            const float vy1 = (y0 + 1 >= 0 && y0 + 1 < HW) ? 1.f : 0.f;
            const int xc0 = min(max(x0, 0), HW - 1), xc1 = min(max(x0 + 1, 0), HW - 1);
            const int yc0 = min(max(y0, 0), HW - 1), yc1 = min(max(y0 + 1, 0), HW - 1);
            const float w00 = (1.f - wx) * (1.f - wy) * vx0 * vy0;
            const float w10 = wx * (1.f - wy) * vx1 * vy0;
            const float w01 = (1.f - wx) * wy * vx0 * vy1;
            const float w11 = wx * wy * vx1 * vy1;

            const __half2* pb = pt_nb + ((size_t)p << 16) * 16;
            auto tap = [&](int yc, int xc, float w) {
                const float4* tp = (const float4*)(pb + (size_t)(yc * HW + xc) * 16);
                union { float4 f; __half2 h[4]; } u4;
                u4.f = tp[g];                          // lanes g=0..3 share one 64B line
                const __half2 wh = __float2half2_rn(w);
                acc4[0] = __hfma2(wh, u4.h[0], acc4[0]);
                acc4[1] = __hfma2(wh, u4.h[1], acc4[1]);
                acc4[2] = __hfma2(wh, u4.h[2], acc4[2]);
                acc4[3] = __hfma2(wh, u4.h[3], acc4[3]);
            };
            tap(yc0, xc0, w00);
            tap(yc0, xc1, w10);
            tap(yc1, xc0, w01);
            tap(yc1, xc1, w11);
        }
        union { __half2 h[4]; f16x8 f; } uf;
        #pragma unroll
        for (int j = 0; j < 4; ++j) uf.h[j] = __hmul2(acc4[j], third);
        a1[Mt] = uf.f;
    }

    // ---- layer 1 via MFMA (A-fragments already in registers) ----
    constexpr float is32 = 0.17677669529663687f;
    #pragma unroll
    for (int Nt = 0; Nt < 4; ++Nt) {
        f32x4 d0 = {0.f, 0.f, 0.f, 0.f};
        f32x4 d1 = {0.f, 0.f, 0.f, 0.f};
        f32x4 d2 = {0.f, 0.f, 0.f, 0.f};
        f32x4 d3 = {0.f, 0.f, 0.f, 0.f};
        d0 = __builtin_amdgcn_mfma_f32_16x16x32_f16(a1[0], b1f[Nt], d0, 0, 0, 0);
        d1 = __builtin_amdgcn_mfma_f32_16x16x32_f16(a1[1], b1f[Nt], d1, 0, 0, 0);
        d2 = __builtin_amdgcn_mfma_f32_16x16x32_f16(a1[2], b1f[Nt], d2, 0, 0, 0);
        d3 = __builtin_amdgcn_mfma_f32_16x16x32_f16(a1[3], b1f[Nt], d3, 0, 0, 0);
        const int hcol = 16 * Nt + ln;
        #pragma unroll
        for (int Mt = 0; Mt < 4; ++Mt) {
            f32x4 dd = (Mt == 0) ? d0 : (Mt == 1) ? d1 : (Mt == 2) ? d2 : d3;
            #pragma unroll
            for (int r = 0; r < 4; ++r) {
                const float hv = softplus_f(fmaf(dd[r], is32, b1v[Nt]));
                const int row = 16 * Mt + 4 * g + r;
                *(__half*)(slice + row * 144 + hcol * 2) = __float2half(hv);
            }
        }
    }

    // ---- layer 2 via MFMA (h transposed through LDS) ----
    f16x8 a2[4][2];
    #pragma unroll
    for (int Mt = 0; Mt < 4; ++Mt)
        #pragma unroll
        for (int kh = 0; kh < 2; ++kh)
            a2[Mt][kh] = *(const f16x8*)(slice + (16 * Mt + ln) * 144 + (kh * 4 + g) * 16);

    #pragma unroll
    for (int Nt2 = 0; Nt2 < 3; ++Nt2) {
        f32x4 e0 = {0.f, 0.f, 0.f, 0.f};
        f32x4 e1 = {0.f, 0.f, 0.f, 0.f};
        f32x4 e2 = {0.f, 0.f, 0.f, 0.f};
        f32x4 e3 = {0.f, 0.f, 0.f, 0.f};
        #pragma unroll
        for (int kh = 0; kh < 2; ++kh) {
            e0 = __builtin_amdgcn_mfma_f32_16x16x32_f16(a2[0][kh], b2f[Nt2][kh], e0, 0, 0, 0);
            e1 = __builtin_amdgcn_mfma_f32_16x16x32_f16(a2[1][kh], b2f[Nt2][kh], e1, 0, 0, 0);
            e2 = __builtin_amdgcn_mfma_f32_16x16x32_f16(a2[2][kh], b2f[Nt2][kh], e2, 0, 0, 0);
            e3 = __builtin_amdgcn_mfma_f32_16x16x32_f16(a2[3][kh], b2f[Nt2][kh], e3, 0, 0, 0);
        }
        const int o = 16 * Nt2 + ln;
        if (o == 0) {
            #pragma unroll
            for (int Mt = 0; Mt < 4; ++Mt) {
                f32x4 ee = (Mt == 0) ? e0 : (Mt == 1) ? e1 : (Mt == 2) ? e2 : e3;
                #pragma unroll
                for (int r = 0; r < 4; ++r) {
                    const int row = 16 * Mt + 4 * g + r;
                    *(float*)(slice + SIGO + row * 4) = fmaf(ee[r], 0.125f, b2v[0]);
                }
            }
        } else if (o < 33) {
            #pragma unroll
            for (int Mt = 0; Mt < 4; ++Mt) {
                f32x4 ee = (Mt == 0) ? e0 : (Mt == 1) ? e1 : (Mt == 2) ? e2 : e3;
                #pragma unroll
                for (int r = 0; r < 4; ++r) {
                    const float vv = fmaf(ee[r], 0.125f, b2v[Nt2]);
                    const float rr = sigmoid_f(vv) * 1.002f - 0.001f;
                    const int row = 16 * Mt + 4 * g + r;
                    *(__half*)(slice + row * 80 + (o - 1) * 2) = __float2half(rr);
                }
            }
        }
    }

    // ---- coalesced stores (nontemporal: keep L2 for the table) ----
    const int q0 = l & 3, r0 = l >> 2;
    #pragma unroll
    for (int q = 0; q < 4; ++q) {
        const int row = 16 * q + r0;
        i32x4 v = *(const i32x4*)(slice + row * 80 + q0 * 16);
        __builtin_nontemporal_store(v,
            (i32x4*)((char*)rgbW + (size_t)(waveBaseS + row) * 64 + q0 * 16));
    }
    const float sv = *(const float*)(slice + SIGO + l * 4);
    __builtin_nontemporal_store(sv, sigW + waveBaseS + l);
}

// ======================= split path: composite =======================
__global__ __launch_bounds__(512)
void k_comp(const __half* __restrict__ rgbW, const float* __restrict__ sigW,
            const float* __restrict__ depths, float* __restrict__ out)
{
    __shared__ float sgS[16 * SAMP];
    __shared__ float dpS[16 * SAMP];
    const int t = threadIdx.x;
    const int rayBase = blockIdx.x * 16;
    for (int i = t; i < 16 * SAMP; i += 512) {
        sgS[i] = sigW[(size_t)rayBase * SAMP + i];
        dpS[i] = depths[(size_t)rayBase * SAMP + i];
    }
    __syncthreads();

    const int rs = t >> 5;          // ray slot 0..15
    const int c = t & 31;           // channel
    const size_t mb = (size_t)(rayBase + rs) * SAMP;
    const ushort* rgbU = (const ushort*)rgbW;

    auto ldr = [&](size_t idx) -> float {
        ushort u = __builtin_nontemporal_load(rgbU + idx);
        __half h = *(__half*)&u;
        return __half2float(h);
    };

    float T = 1.f, a_out = 0.f;
    float sp = sgS[rs * SAMP], dp = dpS[rs * SAMP];
    float rp = ldr(mb * 32 + c);
    float rnx = ldr((mb + 1) * 32 + c);
    #pragma unroll 2
    for (int ss = 1; ss < SAMP; ++ss) {
        const float rc = rnx;
        const int nxt = (ss + 1 < SAMP) ? (ss + 1) : (SAMP - 1);
        rnx = ldr((mb + nxt) * 32 + c);
        const float sc = sgS[rs * SAMP + ss];
        const float dc = dpS[rs * SAMP + ss];
        const float dens = softplus_f(0.5f * (sp + sc) - 1.f);
        const float alpha = 1.f - __expf(-(dc - dp) * dens);
        a_out = fmaf(alpha * T, 0.5f * (rp + rc), a_out);
        T *= 1.f - alpha + 1e-10f;
        sp = sc; dp = dc; rp = rc;
    }
    out[(size_t)(rayBase + rs) * CF + c] = fmaf(a_out, 2.f, -1.f);
}

// ======================= fallback: round-2 fused kernel =======================
constexpr int THREADS = 384;
constexpr int SLICE = 9216;
constexpr int SIG_OFF = 5120;
constexpr int DEP_OFF = 5376;

template<bool USE_WS>
__global__ __launch_bounds__(THREADS)
void k_fused(const float* __restrict__ planes, const __half2* __restrict__ pt,
             const float* __restrict__ coords, const float* __restrict__ depths,
             const float* __restrict__ w1, const float* __restrict__ b1,
             const float* __restrict__ w2, const float* __restrict__ b2,
             float* __restrict__ out)
{
    __shared__ __align__(16) char sm[6 * SLICE];
    const int t = threadIdx.x;
    const int wv = t >> 6;
    const int l = t & 63;
    const int g = l >> 4;
    const int ln = l & 15;
    char* const slice = sm + wv * SLICE;

    const int msamp = blockIdx.x * THREADS + t;
    const int nb = (blockIdx.x >= (NB * RAYS / 4 / 2)) ? 1 : 0;

    f16x8 b1f[4];
    float b1v[4];
    #pragma unroll
    for (int Nt = 0; Nt < 4; ++Nt) {
        const int hn = 16 * Nt + ln;
        const float4* p0 = (const float4*)(w1 + hn * CF + g * 8);
        float4 u = p0[0], v = p0[1];
        b1f[Nt][0] = (_Float16)u.x; b1f[Nt][1] = (_Float16)u.y;
        b1f[Nt][2] = (_Float16)u.z; b1f[Nt][3] = (_Float16)u.w;
        b1f[Nt][4] = (_Float16)v.x; b1f[Nt][5] = (_Float16)v.y;
        b1f[Nt][6] = (_Float16)v.z; b1f[Nt][7] = (_Float16)v.w;
        b1v[Nt] = b1[hn];
    }
    f16x8 b2f[3][2];
    float b2v[3];
    #pragma unroll
    for (int Nt2 = 0; Nt2 < 3; ++Nt2) {
        const int o = 16 * Nt2 + ln;
        if (o < 33) {
            #pragma unroll
            for (int kh = 0; kh < 2; ++kh) {
                const float4* p0 = (const float4*)(w2 + o * HID + kh * 32 + g * 8);
                float4 u = p0[0], v = p0[1];
                b2f[Nt2][kh][0] = (_Float16)u.x; b2f[Nt2][kh][1] = (_Float16)u.y;
                b2f[Nt2][kh][2] = (_Float16)u.z; b2f[Nt2][kh][3] = (_Float16)u.w;
                b2f[Nt2][kh][4] = (_Float16)v.x; b2f[Nt2][kh][5] = (_Float16)v.y;
                b2f[Nt2][kh][6] = (_Float16)v.z; b2f[Nt2][kh][7] = (_Float16)v.w;
            }
            b2v[Nt2] = b2[o];
        } else {
            #pragma unroll
            for (int kh = 0; kh < 2; ++kh)
                #pragma unroll
                for (int i = 0; i < 8; ++i) b2f[Nt2][kh][i] = (_Float16)0.f;
            b2v[Nt2] = 0.f;
        }
    }

    const float* cp = coords + (size_t)msamp * 3;
    const float c0 = cp[0], c1 = cp[1], c2v = cp[2];
    const float myDep = depths[msamp];

    __half2 acc[16];
    #pragma unroll
    for (int k = 0; k < 16; ++k) acc[k] = __float2half2_rn(0.f);
    float xf32[CF];
    if constexpr (!USE_WS) {
        #pragma unroll
        for (int c = 0; c < CF; ++c) xf32[c] = 0.f;
    }

    #pragma unroll
    for (int p = 0; p < 3; ++p) {
        const float u = (p == 2) ? c2v : c0;
        const float v = (p == 0) ? c1 : ((p == 1) ? c2v : c0);
        const float xf = fmaf(u, 128.f, 127.5f);
        const float yf = fmaf(v, 128.f, 127.5f);
        const float x0f = floorf(xf), y0f = floorf(yf);
        const float wx = xf - x0f, wy = yf - y0f;
        const int x0 = (int)x0f, y0 = (int)y0f;
        const float vx0 = (x0 >= 0 && x0 < HW) ? 1.f : 0.f;
        const float vx1 = (x0 + 1 >= 0 && x0 + 1 < HW) ? 1.f : 0.f;
        const float vy0 = (y0 >= 0 && y0 < HW) ? 1.f : 0.f;
        const float vy1 = (y0 + 1 >= 0 && y0 + 1 < HW) ? 1.f : 0.f;
        const int xc0 = min(max(x0, 0), HW - 1), xc1 = min(max(x0 + 1, 0), HW - 1);
        const int yc0 = min(max(y0, 0), HW - 1), yc1 = min(max(y0 + 1, 0), HW - 1);
        const float w00 = (1.f - wx) * (1.f - wy) * vx0 * vy0;
        const float w10 = wx * (1.f - wy) * vx1 * vy0;
        const float w01 = (1.f - wx) * wy * vx0 * vy1;
        const float w11 = wx * wy * vx1 * vy1;

        if constexpr (USE_WS) {
            const __half2* pb = pt + ((size_t)(nb * 3 + p) << 16) * 16;
            auto tap = [&](int yc, int xc, float w) {
                const float4* tp = (const float4*)(pb + (size_t)(yc * HW + xc) * 16);
                const __half2 wh = __float2half2_rn(w);
                #pragma unroll
                for (int q = 0; q < 4; ++q) {
                    union { float4 f; __half2 h[4]; } u4;
                    u4.f = tp[q];
                    acc[q * 4 + 0] = __hfma2(wh, u4.h[0], acc[q * 4 + 0]);
                    acc[q * 4 + 1] = __hfma2(wh, u4.h[1], acc[q * 4 + 1]);
                    acc[q * 4 + 2] = __hfma2(wh, u4.h[2], acc[q * 4 + 2]);
                    acc[q * 4 + 3] = __hfma2(wh, u4.h[3], acc[q * 4 + 3]);
                }
            };
            tap(yc0, xc0, w00);
            tap(yc0, xc1, w10);
            tap(yc1, xc0, w01);
            tap(yc1, xc1, w11);
        } else {
            const float* pb = planes + (((size_t)(nb * 3 + p) * CF) << 16);
            const int i00 = yc0 * HW + xc0, i10 = yc0 * HW + xc1;
            const int i01 = yc1 * HW + xc0, i11 = yc1 * HW + xc1;
            #pragma unroll
            for (int c = 0; c < CF; ++c) {
                const float* pc = pb + ((size_t)c << 16);
                float a0 = fmaf(w00, pc[i00], fmaf(w10, pc[i10], 0.f));
                float a1 = fmaf(w01, pc[i01], fmaf(w11, pc[i11], 0.f));
                xf32[c] += a0 + a1;
            }
        }
    }
    if constexpr (!USE_WS) {
        #pragma unroll
        for (int k = 0; k < 16; ++k)
            acc[k] = __floats2half2_rn(xf32[2 * k], xf32[2 * k + 1]);
    }

    const __half2 third = __float2half2_rn(1.f / 3.f);
    #pragma unroll
    for (int c = 0; c < 4; ++c) {
        union { __half2 h[4]; i32x4 v; } u4;
        #pragma unroll
        for (int j = 0; j < 4; ++j) u4.h[j] = __hmul2(acc[4 * c + j], third);
        *(i32x4*)(slice + l * 80 + c * 16) = u4.v;
    }

    f16x8 a1[4];
    #pragma unroll
    for (int Mt = 0; Mt < 4; ++Mt)
        a1[Mt] = *(const f16x8*)(slice + (16 * Mt + ln) * 80 + g * 16);

    constexpr float is32 = 0.17677669529663687f;
    #pragma unroll
    for (int Nt = 0; Nt < 4; ++Nt) {
        f32x4 d0 = {0.f, 0.f, 0.f, 0.f};
        f32x4 d1 = {0.f, 0.f, 0.f, 0.f};
        f32x4 d2 = {0.f, 0.f, 0.f, 0.f};
        f32x4 d3 = {0.f, 0.f, 0.f, 0.f};
        d0 = __builtin_amdgcn_mfma_f32_16x16x32_f16(a1[0], b1f[Nt], d0, 0, 0, 0);
        d1 = __builtin_amdgcn_mfma_f32_16x16x32_f16(a1[1], b1f[Nt], d1, 0, 0, 0);
        d2 = __builtin_amdgcn_mfma_f32_16x16x32_f16(a1[2], b1f[Nt], d2, 0, 0, 0);
        d3 = __builtin_amdgcn_mfma_f32_16x16x32_f16(a1[3], b1f[Nt], d3, 0, 0, 0);
        const int hcol = 16 * Nt + ln;
        #pragma unroll
        for (int Mt = 0; Mt < 4; ++Mt) {
            f32x4 dd = (Mt == 0) ? d0 : (Mt == 1) ? d1 : (Mt == 2) ? d2 : d3;
            #pragma unroll
            for (int r = 0; r < 4; ++r) {
                const float hv = softplus_f(fmaf(dd[r], is32, b1v[Nt]));
                const int row = 16 * Mt + 4 * g + r;
                *(__half*)(slice + row * 144 + hcol * 2) = __float2half(hv);
            }
        }
    }

    f16x8 a2[4][2];
    #pragma unroll
    for (int Mt = 0; Mt < 4; ++Mt)
        #pragma unroll
        for (int kh = 0; kh < 2; ++kh)
            a2[Mt][kh] = *(const f16x8*)(slice + (16 * Mt + ln) * 144 + (kh * 4 + g) * 16);

    *(float*)(slice + DEP_OFF + l * 4) = myDep;

    #pragma unroll
    for (int Nt2 = 0; Nt2 < 3; ++Nt2) {
        f32x4 e0 = {0.f, 0.f, 0.f, 0.f};
        f32x4 e1 = {0.f, 0.f, 0.f, 0.f};
        f32x4 e2 = {0.f, 0.f, 0.f, 0.f};
        f32x4 e3 = {0.f, 0.f, 0.f, 0.f};
        #pragma unroll
        for (int kh = 0; kh < 2; ++kh) {
            e0 = __builtin_amdgcn_mfma_f32_16x16x32_f16(a2[0][kh], b2f[Nt2][kh], e0, 0, 0, 0);
            e1 = __builtin_amdgcn_mfma_f32_16x16x32_f16(a2[1][kh], b2f[Nt2][kh], e1, 0, 0, 0);
            e2 = __builtin_amdgcn_mfma_f32_16x16x32_f16(a2[2][kh], b2f[Nt2][kh], e2, 0, 0, 0);
            e3 = __builtin_amdgcn_mfma_f32_16x16x32_f16(a2[3][kh], b2f[Nt2][kh], e3, 0, 0, 0);
        }
        const int o = 16 * Nt2 + ln;
        if (o == 0) {
            #pragma unroll
            for (int Mt = 0; Mt < 4; ++Mt) {
                f32x4 ee = (Mt == 0) ? e0 : (Mt == 1) ? e1 : (Mt == 2) ? e2 : e3;
                #pragma unroll
                for (int r = 0; r < 4; ++r) {
                    const int row = 16 * Mt + 4 * g + r;
                    *(float*)(slice + SIG_OFF + row * 4) = fmaf(ee[r], 0.125f, b2v[0]);
                }
            }
        } else if (o < 33) {
            #pragma unroll
            for (int Mt = 0; Mt < 4; ++Mt) {
                f32x4 ee = (Mt == 0) ? e0 : (Mt == 1) ? e1 : (Mt == 2) ? e2 : e3;
                #pragma unroll
                for (int r = 0; r < 4; ++r) {
                    const float vv = fmaf(ee[r], 0.125f, b2v[Nt2]);
                    const float rr = sigmoid_f(vv) * 1.002f - 0.001f;
                    const int row = 16 * Mt + 4 * g + r;
                    *(__half*)(slice + row * 80 + (o + 1) * 2) = __float2half(rr);
                }
            }
        }
    }

    __syncthreads();

    if (t < 128) {
        const int crl = t >> 5;
        const int c = t & 31;
        const int bs = crl * SAMP;
        auto sigAt = [&](int sb) -> float {
            return *(const float*)(sm + (sb >> 6) * SLICE + SIG_OFF + (sb & 63) * 4);
        };
        auto depAt = [&](int sb) -> float {
            return *(const float*)(sm + (sb >> 6) * SLICE + DEP_OFF + (sb & 63) * 4);
        };
        auto rgbAt = [&](int sb) -> float {
            return __half2float(*(const __half*)(sm + (sb >> 6) * SLICE + (sb & 63) * 80 + (c + 1) * 2));
        };
        float T = 1.f, a_out = 0.f;
        float sp = sigAt(bs), dp = depAt(bs), rp = rgbAt(bs);
        for (int ss = 1; ss < SAMP; ++ss) {
            const float sc = sigAt(bs + ss);
            const float dc = depAt(bs + ss);
            const float rc = rgbAt(bs + ss);
            const float dens = softplus_f(0.5f * (sp + sc) - 1.f);
            const float alpha = 1.f - __expf(-(dc - dp) * dens);
            a_out = fmaf(alpha * T, 0.5f * (rp + rc), a_out);
            T *= 1.f - alpha + 1e-10f;
            sp = sc; dp = dc; rp = rc;
        }
        out[(size_t)(blockIdx.x * 4 + crl) * CF + c] = fmaf(a_out, 2.f, -1.f);
    }
}

extern "C" void kernel_launch(void* const* d_in, const int* in_sizes, int n_in,
                              void* d_out, int out_size, void* d_ws, size_t ws_size,
                              hipStream_t stream) {
    (void)in_sizes; (void)n_in; (void)out_size;
    const float* planes = (const float*)d_in[0];
    const float* coords = (const float*)d_in[1];
    const float* depths = (const float*)d_in[2];
    const float* w1 = (const float*)d_in[3];
    const float* b1 = (const float*)d_in[4];
    const float* w2 = (const float*)d_in[5];
    const float* b2 = (const float*)d_in[6];
    float* out = (float*)d_out;

    const size_t ptBytes  = (size_t)NB * 3 * HW * HW * CF * sizeof(__half);   // 25.2 MB
    const size_t rgbBytes = (size_t)M_TOTAL * CF * sizeof(__half);            // 50.3 MB
    const size_t sigBytes = (size_t)M_TOTAL * sizeof(float);                  //  3.1 MB
    const int tgrid = NB * 3 * HW * HW * CF / 2 / 256;                        // 24576

    if (ws_size >= ptBytes + rgbBytes + sigBytes) {
        __half2* pt = (__half2*)d_ws;
        __half* rgbW = (__half*)((char*)d_ws + ptBytes);
        float* sigW = (float*)((char*)d_ws + ptBytes + rgbBytes);
        k_transpose<<<tgrid, 256, 0, stream>>>(planes, pt);
        k_gmlp<<<M_TOTAL / TG, TG, 0, stream>>>(pt, coords, w1, b1, w2, b2, rgbW, sigW);
        k_comp<<<NB * RAYS / 16, 512, 0, stream>>>(rgbW, sigW, depths, out);
    } else if (ws_size >= ptBytes) {
        __half2* pt = (__half2*)d_ws;
        k_transpose<<<tgrid, 256, 0, stream>>>(planes, pt);
        k_fused<true><<<M_TOTAL / THREADS, THREADS, 0, stream>>>(planes, pt, coords, depths,
                                                                 w1, b1, w2, b2, out);
    } else {
        k_fused<false><<<M_TOTAL / THREADS, THREADS, 0, stream>>>(planes, nullptr, coords, depths,
                                                                  w1, b1, w2, b2, out);
    }
}

// Round 8
// 171.832 us; speedup vs baseline: 1.3948x; 1.0994x over previous
//
#include <hip/hip_runtime.h>
#include <hip/hip_fp16.h>

#define NB 2
#define RAYS 4096
#define SAMP 96
#define CF 32
#define HID 64
#define HW 256

constexpr int M_TOTAL = NB * RAYS * SAMP;   // 786432 samples

typedef _Float16 f16x8 __attribute__((ext_vector_type(8)));
typedef float f32x4 __attribute__((ext_vector_type(4)));
typedef int i32x4 __attribute__((ext_vector_type(4)));

__device__ __forceinline__ float softplus_f(float z) {
    return fmaxf(z, 0.f) + __logf(1.f + __expf(-fabsf(z)));
}
__device__ __forceinline__ float sigmoid_f(float z) {
    return __fdividef(1.f, 1.f + __expf(-z));
}

// planes (N,3,C,H,W) f32 -> pt (N*3, H, W, C) f16, coalesced both sides:
// thread = one (pn,xy); loop over 16 channel-pairs. Per load-inst a wave
// touches 4 contiguous 64B lines; stores are 1KB contiguous per wave.
__global__ __launch_bounds__(256)
void k_transpose(const float* __restrict__ src, __half2* __restrict__ dst) {
    const int i = blockIdx.x * 256 + threadIdx.x;   // over 6*65536 texels
    const int xy = i & 0xFFFF;
    const int pn = i >> 16;                          // n*3+p in [0,6)
    const float* s = src + (((size_t)pn * CF) << 16) + xy;
    __half2 v[16];
    #pragma unroll
    for (int c2 = 0; c2 < 16; ++c2) {
        const float a = s[((size_t)(2 * c2)) << 16];
        const float b = s[((size_t)(2 * c2 + 1)) << 16];
        v[c2] = __floats2half2_rn(a, b);
    }
    __half2* d = dst + (size_t)i * 16;
    #pragma unroll
    for (int q = 0; q < 4; ++q)
        ((i32x4*)d)[q] = ((const i32x4*)v)[q];
}

// ============== fused gather + MLP + composite ==============
// TG=192 (3 waves) = exactly 2 rays (96 samples each): block composites its
// own rays from LDS -> no rgb/sig workspace round-trip, no k_comp launch.
// Gather stays 4-lane cooperative (r7: TA line-probes 4x down, -24%).
// LDS 3*9216=27.6KB -> 5 blocks/CU; natural VGPR (r5: min-occ clamp spills).
constexpr int TG3 = 192;
constexpr int SLICE_A = 9216;   // per-wave LDS slice bytes
constexpr int SIGO = 5120;      // sigma  region (float[64])
constexpr int DEPO = 5376;      // depth  region (float[64])
// rgb: row*80 + c*2 (c=0..31); hS: row*144 (overlaps, sequenced via regs)

__global__ __launch_bounds__(TG3)
void k_gmlp3(const __half2* __restrict__ pt, const float* __restrict__ coords,
             const float* __restrict__ depths,
             const float* __restrict__ w1, const float* __restrict__ b1,
             const float* __restrict__ w2, const float* __restrict__ b2,
             float* __restrict__ out)
{
    __shared__ __align__(16) char sm[3 * SLICE_A];
    const int t = threadIdx.x;
    const int wv = t >> 6;
    const int l = t & 63;
    const int g = l >> 4;
    const int ln = l & 15;
    char* const slice = sm + wv * SLICE_A;

    // ---- weight fragments in registers ----
    f16x8 b1f[4];
    float b1v[4];
    #pragma unroll
    for (int Nt = 0; Nt < 4; ++Nt) {
        const int hn = 16 * Nt + ln;
        const float4* p0 = (const float4*)(w1 + hn * CF + g * 8);
        float4 u = p0[0], v = p0[1];
        b1f[Nt][0] = (_Float16)u.x; b1f[Nt][1] = (_Float16)u.y;
        b1f[Nt][2] = (_Float16)u.z; b1f[Nt][3] = (_Float16)u.w;
        b1f[Nt][4] = (_Float16)v.x; b1f[Nt][5] = (_Float16)v.y;
        b1f[Nt][6] = (_Float16)v.z; b1f[Nt][7] = (_Float16)v.w;
        b1v[Nt] = b1[hn];
    }
    f16x8 b2f[3][2];
    float b2v[3];
    #pragma unroll
    for (int Nt2 = 0; Nt2 < 3; ++Nt2) {
        const int o = 16 * Nt2 + ln;
        if (o < 33) {
            #pragma unroll
            for (int kh = 0; kh < 2; ++kh) {
                const float4* p0 = (const float4*)(w2 + o * HID + kh * 32 + g * 8);
                float4 u = p0[0], v = p0[1];
                b2f[Nt2][kh][0] = (_Float16)u.x; b2f[Nt2][kh][1] = (_Float16)u.y;
                b2f[Nt2][kh][2] = (_Float16)u.z; b2f[Nt2][kh][3] = (_Float16)u.w;
                b2f[Nt2][kh][4] = (_Float16)v.x; b2f[Nt2][kh][5] = (_Float16)v.y;
                b2f[Nt2][kh][6] = (_Float16)v.z; b2f[Nt2][kh][7] = (_Float16)v.w;
            }
            b2v[Nt2] = b2[o];
        } else {
            #pragma unroll
            for (int kh = 0; kh < 2; ++kh)
                #pragma unroll
                for (int i = 0; i < 8; ++i) b2f[Nt2][kh][i] = (_Float16)0.f;
            b2v[Nt2] = 0.f;
        }
    }

    // ---- gather: 4-lane-coalesced taps, A-fragments built in registers ----
    const int waveBaseS = blockIdx.x * TG3 + wv * 64;
    const int nb = (waveBaseS >= M_TOTAL / NB) ? 1 : 0;
    const __half2* pt_nb = pt + (((size_t)nb * 3) << 16) * 16;
    const __half2 third = __float2half2_rn(1.f / 3.f);
    const float myDep = depths[waveBaseS + l];

    f16x8 a1[4];
    #pragma unroll
    for (int Mt = 0; Mt < 4; ++Mt) {
        const int smp = waveBaseS + 16 * Mt + ln;
        const float* cp = coords + (size_t)smp * 3;
        const float c0 = cp[0], c1 = cp[1], c2v = cp[2];
        __half2 acc4[4];
        #pragma unroll
        for (int j = 0; j < 4; ++j) acc4[j] = __float2half2_rn(0.f);

        #pragma unroll
        for (int p = 0; p < 3; ++p) {
            const float u = (p == 2) ? c2v : c0;
            const float v = (p == 0) ? c1 : ((p == 1) ? c2v : c0);
            const float xf = fmaf(u, 128.f, 127.5f);
            const float yf = fmaf(v, 128.f, 127.5f);
            const float x0f = floorf(xf), y0f = floorf(yf);
            const float wx = xf - x0f, wy = yf - y0f;
            const int x0 = (int)x0f, y0 = (int)y0f;
            const float vx0 = (x0 >= 0 && x0 < HW) ? 1.f : 0.f;
            const float vx1 = (x0 + 1 >= 0 && x0 + 1 < HW) ? 1.f : 0.f;
            const float vy0 = (y0 >= 0 && y0 < HW) ? 1.f : 0.f;
            const float vy1 = (y0 + 1 >= 0 && y0 + 1 < HW) ? 1.f : 0.f;
            const int xc0 = min(max(x0, 0), HW - 1), xc1 = min(max(x0 + 1, 0), HW - 1);
            const int yc0 = min(max(y0, 0), HW - 1), yc1 = min(max(y0 + 1, 0), HW - 1);
            const float w00 = (1.f - wx) * (1.f - wy) * vx0 * vy0;
            const float w10 = wx * (1.f - wy) * vx1 * vy0;
            const float w01 = (1.f - wx) * wy * vx0 * vy1;
            const float w11 = wx * wy * vx1 * vy1;

            const __half2* pb = pt_nb + ((size_t)p << 16) * 16;
            auto tap = [&](int yc, int xc, float w) {
                const float4* tp = (const float4*)(pb + (size_t)(yc * HW + xc) * 16);
                union { float4 f; __half2 h[4]; } u4;
                u4.f = tp[g];                          // lanes g=0..3 share one 64B line
                const __half2 wh = __float2half2_rn(w);
                acc4[0] = __hfma2(wh, u4.h[0], acc4[0]);
                acc4[1] = __hfma2(wh, u4.h[1], acc4[1]);
                acc4[2] = __hfma2(wh, u4.h[2], acc4[2]);
                acc4[3] = __hfma2(wh, u4.h[3], acc4[3]);
            };
            tap(yc0, xc0, w00);
            tap(yc0, xc1, w10);
            tap(yc1, xc0, w01);
            tap(yc1, xc1, w11);
        }
        union { __half2 h[4]; f16x8 f; } uf;
        #pragma unroll
        for (int j = 0; j < 4; ++j) uf.h[j] = __hmul2(acc4[j], third);
        a1[Mt] = uf.f;
    }

    // ---- layer 1 via MFMA ----
    constexpr float is32 = 0.17677669529663687f;
    #pragma unroll
    for (int Nt = 0; Nt < 4; ++Nt) {
        f32x4 d0 = {0.f, 0.f, 0.f, 0.f};
        f32x4 d1 = {0.f, 0.f, 0.f, 0.f};
        f32x4 d2 = {0.f, 0.f, 0.f, 0.f};
        f32x4 d3 = {0.f, 0.f, 0.f, 0.f};
        d0 = __builtin_amdgcn_mfma_f32_16x16x32_f16(a1[0], b1f[Nt], d0, 0, 0, 0);
        d1 = __builtin_amdgcn_mfma_f32_16x16x32_f16(a1[1], b1f[Nt], d1, 0, 0, 0);
        d2 = __builtin_amdgcn_mfma_f32_16x16x32_f16(a1[2], b1f[Nt], d2, 0, 0, 0);
        d3 = __builtin_amdgcn_mfma_f32_16x16x32_f16(a1[3], b1f[Nt], d3, 0, 0, 0);
        const int hcol = 16 * Nt + ln;
        #pragma unroll
        for (int Mt = 0; Mt < 4; ++Mt) {
            f32x4 dd = (Mt == 0) ? d0 : (Mt == 1) ? d1 : (Mt == 2) ? d2 : d3;
            #pragma unroll
            for (int r = 0; r < 4; ++r) {
                const float hv = softplus_f(fmaf(dd[r], is32, b1v[Nt]));
                const int row = 16 * Mt + 4 * g + r;
                *(__half*)(slice + row * 144 + hcol * 2) = __float2half(hv);
            }
        }
    }

    // ---- layer 2 via MFMA (h transposed through LDS) ----
    f16x8 a2[4][2];
    #pragma unroll
    for (int Mt = 0; Mt < 4; ++Mt)
        #pragma unroll
        for (int kh = 0; kh < 2; ++kh)
            a2[Mt][kh] = *(const f16x8*)(slice + (16 * Mt + ln) * 144 + (kh * 4 + g) * 16);

    // hS dead now -> safe to overwrite slice with rgb/sig/dep
    *(float*)(slice + DEPO + l * 4) = myDep;

    #pragma unroll
    for (int Nt2 = 0; Nt2 < 3; ++Nt2) {
        f32x4 e0 = {0.f, 0.f, 0.f, 0.f};
        f32x4 e1 = {0.f, 0.f, 0.f, 0.f};
        f32x4 e2 = {0.f, 0.f, 0.f, 0.f};
        f32x4 e3 = {0.f, 0.f, 0.f, 0.f};
        #pragma unroll
        for (int kh = 0; kh < 2; ++kh) {
            e0 = __builtin_amdgcn_mfma_f32_16x16x32_f16(a2[0][kh], b2f[Nt2][kh], e0, 0, 0, 0);
            e1 = __builtin_amdgcn_mfma_f32_16x16x32_f16(a2[1][kh], b2f[Nt2][kh], e1, 0, 0, 0);
            e2 = __builtin_amdgcn_mfma_f32_16x16x32_f16(a2[2][kh], b2f[Nt2][kh], e2, 0, 0, 0);
            e3 = __builtin_amdgcn_mfma_f32_16x16x32_f16(a2[3][kh], b2f[Nt2][kh], e3, 0, 0, 0);
        }
        const int o = 16 * Nt2 + ln;
        if (o == 0) {
            #pragma unroll
            for (int Mt = 0; Mt < 4; ++Mt) {
                f32x4 ee = (Mt == 0) ? e0 : (Mt == 1) ? e1 : (Mt == 2) ? e2 : e3;
                #pragma unroll
                for (int r = 0; r < 4; ++r) {
                    const int row = 16 * Mt + 4 * g + r;
                    *(float*)(slice + SIGO + row * 4) = fmaf(ee[r], 0.125f, b2v[0]);
                }
            }
        } else if (o < 33) {
            #pragma unroll
            for (int Mt = 0; Mt < 4; ++Mt) {
                f32x4 ee = (Mt == 0) ? e0 : (Mt == 1) ? e1 : (Mt == 2) ? e2 : e3;
                #pragma unroll
                for (int r = 0; r < 4; ++r) {
                    const float vv = fmaf(ee[r], 0.125f, b2v[Nt2]);
                    const float rr = sigmoid_f(vv) * 1.002f - 0.001f;
                    const int row = 16 * Mt + 4 * g + r;
                    *(__half*)(slice + row * 80 + (o - 1) * 2) = __float2half(rr);
                }
            }
        }
    }

    __syncthreads();

    // ---- composite: 2 rays x 32 channels = threads 0..63 ----
    if (t < 64) {
        const int rl = t >> 5;          // ray within block
        const int c = t & 31;           // channel
        const int bs = rl * SAMP;       // base sample within block
        auto sigAt = [&](int sb) -> float {
            return *(const float*)(sm + (sb >> 6) * SLICE_A + SIGO + (sb & 63) * 4);
        };
        auto depAt = [&](int sb) -> float {
            return *(const float*)(sm + (sb >> 6) * SLICE_A + DEPO + (sb & 63) * 4);
        };
        auto rgbAt = [&](int sb) -> float {
            return __half2float(*(const __half*)(sm + (sb >> 6) * SLICE_A + (sb & 63) * 80 + c * 2));
        };
        float T = 1.f, a_out = 0.f;
        float sp = sigAt(bs), dp = depAt(bs), rp = rgbAt(bs);
        for (int ss = 1; ss < SAMP; ++ss) {
            const float sc = sigAt(bs + ss);
            const float dc = depAt(bs + ss);
            const float rc = rgbAt(bs + ss);
            const float dens = softplus_f(0.5f * (sp + sc) - 1.f);
            const float alpha = 1.f - __expf(-(dc - dp) * dens);
            a_out = fmaf(alpha * T, 0.5f * (rp + rc), a_out);
            T *= 1.f - alpha + 1e-10f;
            sp = sc; dp = dc; rp = rc;
        }
        out[(size_t)(blockIdx.x * 2 + rl) * CF + c] = fmaf(a_out, 2.f, -1.f);
    }
}

// ======================= fallback: fused, original layout =======================
constexpr int THREADS = 384;
constexpr int SLICE = 9216;
constexpr int SIG_OFF = 5120;
constexpr int DEP_OFF = 5376;

__global__ __launch_bounds__(THREADS)
void k_fused(const float* __restrict__ planes,
             const float* __restrict__ coords, const float* __restrict__ depths,
             const float* __restrict__ w1, const float* __restrict__ b1,
             const float* __restrict__ w2, const float* __restrict__ b2,
             float* __restrict__ out)
{
    __shared__ __align__(16) char sm[6 * SLICE];
    const int t = threadIdx.x;
    const int wv = t >> 6;
    const int l = t & 63;
    const int g = l >> 4;
    const int ln = l & 15;
    char* const slice = sm + wv * SLICE;

    const int msamp = blockIdx.x * THREADS + t;
    const int nb = (msamp >= M_TOTAL / NB) ? 1 : 0;

    f16x8 b1f[4];
    float b1v[4];
    #pragma unroll
    for (int Nt = 0; Nt < 4; ++Nt) {
        const int hn = 16 * Nt + ln;
        const float4* p0 = (const float4*)(w1 + hn * CF + g * 8);
        float4 u = p0[0], v = p0[1];
        b1f[Nt][0] = (_Float16)u.x; b1f[Nt][1] = (_Float16)u.y;
        b1f[Nt][2] = (_Float16)u.z; b1f[Nt][3] = (_Float16)u.w;
        b1f[Nt][4] = (_Float16)v.x; b1f[Nt][5] = (_Float16)v.y;
        b1f[Nt][6] = (_Float16)v.z; b1f[Nt][7] = (_Float16)v.w;
        b1v[Nt] = b1[hn];
    }
    f16x8 b2f[3][2];
    float b2v[3];
    #pragma unroll
    for (int Nt2 = 0; Nt2 < 3; ++Nt2) {
        const int o = 16 * Nt2 + ln;
        if (o < 33) {
            #pragma unroll
            for (int kh = 0; kh < 2; ++kh) {
                const float4* p0 = (const float4*)(w2 + o * HID + kh * 32 + g * 8);
                float4 u = p0[0], v = p0[1];
                b2f[Nt2][kh][0] = (_Float16)u.x; b2f[Nt2][kh][1] = (_Float16)u.y;
                b2f[Nt2][kh][2] = (_Float16)u.z; b2f[Nt2][kh][3] = (_Float16)u.w;
                b2f[Nt2][kh][4] = (_Float16)v.x; b2f[Nt2][kh][5] = (_Float16)v.y;
                b2f[Nt2][kh][6] = (_Float16)v.z; b2f[Nt2][kh][7] = (_Float16)v.w;
            }
            b2v[Nt2] = b2[o];
        } else {
            #pragma unroll
            for (int kh = 0; kh < 2; ++kh)
                #pragma unroll
                for (int i = 0; i < 8; ++i) b2f[Nt2][kh][i] = (_Float16)0.f;
            b2v[Nt2] = 0.f;
        }
    }

    const float* cp = coords + (size_t)msamp * 3;
    const float c0 = cp[0], c1 = cp[1], c2v = cp[2];
    const float myDep = depths[msamp];

    float xf32[CF];
    #pragma unroll
    for (int c = 0; c < CF; ++c) xf32[c] = 0.f;

    #pragma unroll
    for (int p = 0; p < 3; ++p) {
        const float u = (p == 2) ? c2v : c0;
        const float v = (p == 0) ? c1 : ((p == 1) ? c2v : c0);
        const float xf = fmaf(u, 128.f, 127.5f);
        const float yf = fmaf(v, 128.f, 127.5f);
        const float x0f = floorf(xf), y0f = floorf(yf);
        const float wx = xf - x0f, wy = yf - y0f;
        const int x0 = (int)x0f, y0 = (int)y0f;
        const float vx0 = (x0 >= 0 && x0 < HW) ? 1.f : 0.f;
        const float vx1 = (x0 + 1 >= 0 && x0 + 1 < HW) ? 1.f : 0.f;
        const float vy0 = (y0 >= 0 && y0 < HW) ? 1.f : 0.f;
        const float vy1 = (y0 + 1 >= 0 && y0 + 1 < HW) ? 1.f : 0.f;
        const int xc0 = min(max(x0, 0), HW - 1), xc1 = min(max(x0 + 1, 0), HW - 1);
        const int yc0 = min(max(y0, 0), HW - 1), yc1 = min(max(y0 + 1, 0), HW - 1);
        const float w00 = (1.f - wx) * (1.f - wy) * vx0 * vy0;
        const float w10 = wx * (1.f - wy) * vx1 * vy0;
        const float w01 = (1.f - wx) * wy * vx0 * vy1;
        const float w11 = wx * wy * vx1 * vy1;

        const float* pb = planes + (((size_t)(nb * 3 + p) * CF) << 16);
        const int i00 = yc0 * HW + xc0, i10 = yc0 * HW + xc1;
        const int i01 = yc1 * HW + xc0, i11 = yc1 * HW + xc1;
        #pragma unroll
        for (int c = 0; c < CF; ++c) {
            const float* pc = pb + ((size_t)c << 16);
            float a0 = fmaf(w00, pc[i00], fmaf(w10, pc[i10], 0.f));
            float a1 = fmaf(w01, pc[i01], fmaf(w11, pc[i11], 0.f));
            xf32[c] += a0 + a1;
        }
    }

    #pragma unroll
    for (int c = 0; c < 4; ++c) {
        union { __half2 h[4]; i32x4 v; } u4;
        #pragma unroll
        for (int j = 0; j < 4; ++j)
            u4.h[j] = __floats2half2_rn(xf32[8 * c + 2 * j] * (1.f / 3.f),
                                        xf32[8 * c + 2 * j + 1] * (1.f / 3.f));
        *(i32x4*)(slice + l * 80 + c * 16) = u4.v;
    }

    f16x8 a1[4];
    #pragma unroll
    for (int Mt = 0; Mt < 4; ++Mt)
        a1[Mt] = *(const f16x8*)(slice + (16 * Mt + ln) * 80 + g * 16);

    constexpr float is32 = 0.17677669529663687f;
    #pragma unroll
    for (int Nt = 0; Nt < 4; ++Nt) {
        f32x4 d0 = {0.f, 0.f, 0.f, 0.f};
        f32x4 d1 = {0.f, 0.f, 0.f, 0.f};
        f32x4 d2 = {0.f, 0.f, 0.f, 0.f};
        f32x4 d3 = {0.f, 0.f, 0.f, 0.f};
        d0 = __builtin_amdgcn_mfma_f32_16x16x32_f16(a1[0], b1f[Nt], d0, 0, 0, 0);
        d1 = __builtin_amdgcn_mfma_f32_16x16x32_f16(a1[1], b1f[Nt], d1, 0, 0, 0);
        d2 = __builtin_amdgcn_mfma_f32_16x16x32_f16(a1[2], b1f[Nt], d2, 0, 0, 0);
        d3 = __builtin_amdgcn_mfma_f32_16x16x32_f16(a1[3], b1f[Nt], d3, 0, 0, 0);
        const int hcol = 16 * Nt + ln;
        #pragma unroll
        for (int Mt = 0; Mt < 4; ++Mt) {
            f32x4 dd = (Mt == 0) ? d0 : (Mt == 1) ? d1 : (Mt == 2) ? d2 : d3;
            #pragma unroll
            for (int r = 0; r < 4; ++r) {
                const float hv = softplus_f(fmaf(dd[r], is32, b1v[Nt]));
                const int row = 16 * Mt + 4 * g + r;
                *(__half*)(slice + row * 144 + hcol * 2) = __float2half(hv);
            }
        }
    }

    f16x8 a2[4][2];
    #pragma unroll
    for (int Mt = 0; Mt < 4; ++Mt)
        #pragma unroll
        for (int kh = 0; kh < 2; ++kh)
            a2[Mt][kh] = *(const f16x8*)(slice + (16 * Mt + ln) * 144 + (kh * 4 + g) * 16);

    *(float*)(slice + DEP_OFF + l * 4) = myDep;

    #pragma unroll
    for (int Nt2 = 0; Nt2 < 3; ++Nt2) {
        f32x4 e0 = {0.f, 0.f, 0.f, 0.f};
        f32x4 e1 = {0.f, 0.f, 0.f, 0.f};
        f32x4 e2 = {0.f, 0.f, 0.f, 0.f};
        f32x4 e3 = {0.f, 0.f, 0.f, 0.f};
        #pragma unroll
        for (int kh = 0; kh < 2; ++kh) {
            e0 = __builtin_amdgcn_mfma_f32_16x16x32_f16(a2[0][kh], b2f[Nt2][kh], e0, 0, 0, 0);
            e1 = __builtin_amdgcn_mfma_f32_16x16x32_f16(a2[1][kh], b2f[Nt2][kh], e1, 0, 0, 0);
            e2 = __builtin_amdgcn_mfma_f32_16x16x32_f16(a2[2][kh], b2f[Nt2][kh], e2, 0, 0, 0);
            e3 = __builtin_amdgcn_mfma_f32_16x16x32_f16(a2[3][kh], b2f[Nt2][kh], e3, 0, 0, 0);
        }
        const int o = 16 * Nt2 + ln;
        if (o == 0) {
            #pragma unroll
            for (int Mt = 0; Mt < 4; ++Mt) {
                f32x4 ee = (Mt == 0) ? e0 : (Mt == 1) ? e1 : (Mt == 2) ? e2 : e3;
                #pragma unroll
                for (int r = 0; r < 4; ++r) {
                    const int row = 16 * Mt + 4 * g + r;
                    *(float*)(slice + SIG_OFF + row * 4) = fmaf(ee[r], 0.125f, b2v[0]);
                }
            }
        } else if (o < 33) {
            #pragma unroll
            for (int Mt = 0; Mt < 4; ++Mt) {
                f32x4 ee = (Mt == 0) ? e0 : (Mt == 1) ? e1 : (Mt == 2) ? e2 : e3;
                #pragma unroll
                for (int r = 0; r < 4; ++r) {
                    const float vv = fmaf(ee[r], 0.125f, b2v[Nt2]);
                    const float rr = sigmoid_f(vv) * 1.002f - 0.001f;
                    const int row = 16 * Mt + 4 * g + r;
                    *(__half*)(slice + row * 80 + (o + 1) * 2) = __float2half(rr);
                }
            }
        }
    }

    __syncthreads();

    if (t < 128) {
        const int crl = t >> 5;
        const int c = t & 31;
        const int bs = crl * SAMP;
        auto sigAt = [&](int sb) -> float {
            return *(const float*)(sm + (sb >> 6) * SLICE + SIG_OFF + (sb & 63) * 4);
        };
        auto depAt = [&](int sb) -> float {
            return *(const float*)(sm + (sb >> 6) * SLICE + DEP_OFF + (sb & 63) * 4);
        };
        auto rgbAt = [&](int sb) -> float {
            return __half2float(*(const __half*)(sm + (sb >> 6) * SLICE + (sb & 63) * 80 + (c + 1) * 2));
        };
        float T = 1.f, a_out = 0.f;
        float sp = sigAt(bs), dp = depAt(bs), rp = rgbAt(bs);
        for (int ss = 1; ss < SAMP; ++ss) {
            const float sc = sigAt(bs + ss);
            const float dc = depAt(bs + ss);
            const float rc = rgbAt(bs + ss);
            const float dens = softplus_f(0.5f * (sp + sc) - 1.f);
            const float alpha = 1.f - __expf(-(dc - dp) * dens);
            a_out = fmaf(alpha * T, 0.5f * (rp + rc), a_out);
            T *= 1.f - alpha + 1e-10f;
            sp = sc; dp = dc; rp = rc;
        }
        out[(size_t)(blockIdx.x * 4 + crl) * CF + c] = fmaf(a_out, 2.f, -1.f);
    }
}

extern "C" void kernel_launch(void* const* d_in, const int* in_sizes, int n_in,
                              void* d_out, int out_size, void* d_ws, size_t ws_size,
                              hipStream_t stream) {
    (void)in_sizes; (void)n_in; (void)out_size;
    const float* planes = (const float*)d_in[0];
    const float* coords = (const float*)d_in[1];
    const float* depths = (const float*)d_in[2];
    const float* w1 = (const float*)d_in[3];
    const float* b1 = (const float*)d_in[4];
    const float* w2 = (const float*)d_in[5];
    const float* b2 = (const float*)d_in[6];
    float* out = (float*)d_out;

    const size_t ptBytes = (size_t)NB * 3 * HW * HW * CF * sizeof(__half);   // 25.2 MB
    const int tgrid = NB * 3 * HW * HW / 256;                                 // 1536

    if (ws_size >= ptBytes) {
        __half2* pt = (__half2*)d_ws;
        k_transpose<<<tgrid, 256, 0, stream>>>(planes, pt);
        k_gmlp3<<<M_TOTAL / TG3, TG3, 0, stream>>>(pt, coords, depths,
                                                   w1, b1, w2, b2, out);
    } else {
        k_fused<<<M_TOTAL / THREADS, THREADS, 0, stream>>>(planes, coords, depths,
                                                           w1, b1, w2, b2, out);
    }
}